// Round 2
// baseline (758.193 us; speedup 1.0000x reference)
//
#include <hip/hip_runtime.h>

#define FD 128

// ---------------- graph preprocessing ----------------
__global__ __launch_bounds__(256) void init_kernel(int* __restrict__ deg, int* __restrict__ fill, int n) {
  int i = blockIdx.x * 256 + threadIdx.x;
  if (i < n) { deg[i] = 1; fill[i] = 0; }
}

// edge_index arrives as int32 (harness converts integer inputs to int): ei[0..e) = row(src), ei[e..2e) = col(dst)
__global__ __launch_bounds__(256) void edge_count_kernel(const int* __restrict__ ei, int e, int* __restrict__ deg) {
  int i = blockIdx.x * 256 + threadIdx.x;
  if (i < e) atomicAdd(&deg[ei[e + i]], 1);
}

__global__ __launch_bounds__(256) void dinv_kernel(const int* __restrict__ deg, float* __restrict__ dinv, int n) {
  int i = blockIdx.x * 256 + threadIdx.x;
  if (i < n) dinv[i] = rsqrtf((float)deg[i]);
}

__global__ __launch_bounds__(128) void scan1_kernel(const int* __restrict__ deg, int n, int* __restrict__ tmp, int* __restrict__ partials) {
  __shared__ int s[128];
  int b = blockIdx.x, t = threadIdx.x;
  int i = b * 128 + t;
  s[t] = (i < n) ? (deg[i] - 1) : 0;
  __syncthreads();
  for (int off = 1; off < 128; off <<= 1) {
    int u = (t >= off) ? s[t - off] : 0;
    __syncthreads();
    s[t] += u;
    __syncthreads();
  }
  if (i < n) tmp[i] = s[t];
  if (t == 127) partials[b] = s[127];
}

__global__ __launch_bounds__(1024) void scan2_kernel(int* __restrict__ partials, int nb) {
  __shared__ int s[1024];
  int t = threadIdx.x;
  s[t] = (t < nb) ? partials[t] : 0;
  __syncthreads();
  for (int off = 1; off < 1024; off <<= 1) {
    int u = (t >= off) ? s[t - off] : 0;
    __syncthreads();
    s[t] += u;
    __syncthreads();
  }
  if (t < nb) partials[t] = (t == 0) ? 0 : s[t - 1];
}

__global__ __launch_bounds__(128) void scan3_kernel(const int* __restrict__ tmp, const int* __restrict__ partials, int* __restrict__ indptr, int n) {
  int i = blockIdx.x * 128 + threadIdx.x;
  if (i < n) indptr[i + 1] = tmp[i] + partials[blockIdx.x];
  if (i == 0) indptr[0] = 0;
}

__global__ __launch_bounds__(256) void fill_kernel(const int* __restrict__ ei, int e,
    const int* __restrict__ indptr, int* __restrict__ fill, const float* __restrict__ dinv,
    int* __restrict__ csr_src, float* __restrict__ csr_norm) {
  int i = blockIdx.x * 256 + threadIdx.x;
  if (i < e) {
    int r = ei[i];
    int c = ei[e + i];
    int pos = indptr[c] + atomicAdd(&fill[c], 1);
    csr_src[pos] = r;
    csr_norm[pos] = dinv[r] * dinv[c];
  }
}

// ---------------- GEMM: C[n,128] = A[n,128] @ W[128,128] (+ epilogues) ----------------
// EPI 0: C = A@W
// EPI 1: C = relu(agg*s + t) + A@W          (layer-0 apply fused with proj GEMM)
// EPI 2: C = relu(A@W + bias)               (MLP)
template<int EPI>
__global__ __launch_bounds__(256) void gemm128(const float* __restrict__ A, const float* __restrict__ W,
    float* __restrict__ C, int n,
    const float* __restrict__ agg, const float* __restrict__ sv, const float* __restrict__ tv,
    const float* __restrict__ bias)
{
  __shared__ float xs_[64][33];   // padded: conflict-free column reads
  __shared__ float ws_[32][128];
  const int tid = threadIdx.x;
  const int row0 = blockIdx.x * 64;
  const int cg = tid & 15;   // 16 col groups
  const int rg = tid >> 4;   // 16 row groups
  float acc[4][8];
  #pragma unroll
  for (int i = 0; i < 4; ++i)
    #pragma unroll
    for (int j = 0; j < 8; ++j) acc[i][j] = 0.f;

  for (int k0 = 0; k0 < FD; k0 += 32) {
    #pragma unroll
    for (int i = 0; i < 2; ++i) {
      int j = tid + 256 * i;
      int r = j >> 3, c4 = (j & 7) * 4;
      int gr = row0 + r;
      float4 v = make_float4(0.f, 0.f, 0.f, 0.f);
      if (gr < n) v = *(const float4*)&A[gr * FD + k0 + c4];
      xs_[r][c4] = v.x; xs_[r][c4 + 1] = v.y; xs_[r][c4 + 2] = v.z; xs_[r][c4 + 3] = v.w;
    }
    #pragma unroll
    for (int i = 0; i < 4; ++i) {
      int j = tid + 256 * i;
      int r = j >> 5, c4 = (j & 31) * 4;
      *(float4*)&ws_[r][c4] = *(const float4*)&W[(k0 + r) * FD + c4];
    }
    __syncthreads();
    #pragma unroll
    for (int kk = 0; kk < 32; ++kk) {
      float xv[4];
      #pragma unroll
      for (int i = 0; i < 4; ++i) xv[i] = xs_[rg * 4 + i][kk];
      float4 wa = *(const float4*)&ws_[kk][cg * 4];
      float4 wb = *(const float4*)&ws_[kk][64 + cg * 4];
      #pragma unroll
      for (int i = 0; i < 4; ++i) {
        acc[i][0] += xv[i] * wa.x; acc[i][1] += xv[i] * wa.y;
        acc[i][2] += xv[i] * wa.z; acc[i][3] += xv[i] * wa.w;
        acc[i][4] += xv[i] * wb.x; acc[i][5] += xv[i] * wb.y;
        acc[i][6] += xv[i] * wb.z; acc[i][7] += xv[i] * wb.w;
      }
    }
    __syncthreads();
  }

  const int cA = cg * 4, cB = 64 + cg * 4;
  #pragma unroll
  for (int i = 0; i < 4; ++i) {
    int gr = row0 + rg * 4 + i;
    if (gr >= n) continue;
    float4 va = make_float4(acc[i][0], acc[i][1], acc[i][2], acc[i][3]);
    float4 vb = make_float4(acc[i][4], acc[i][5], acc[i][6], acc[i][7]);
    if (EPI == 1) {
      float4 a = *(const float4*)&agg[gr * FD + cA];
      float4 s = *(const float4*)&sv[cA];
      float4 t = *(const float4*)&tv[cA];
      va.x += fmaxf(a.x * s.x + t.x, 0.f);
      va.y += fmaxf(a.y * s.y + t.y, 0.f);
      va.z += fmaxf(a.z * s.z + t.z, 0.f);
      va.w += fmaxf(a.w * s.w + t.w, 0.f);
      a = *(const float4*)&agg[gr * FD + cB];
      s = *(const float4*)&sv[cB];
      t = *(const float4*)&tv[cB];
      vb.x += fmaxf(a.x * s.x + t.x, 0.f);
      vb.y += fmaxf(a.y * s.y + t.y, 0.f);
      vb.z += fmaxf(a.z * s.z + t.z, 0.f);
      vb.w += fmaxf(a.w * s.w + t.w, 0.f);
    } else if (EPI == 2) {
      float4 b = *(const float4*)&bias[cA];
      va.x = fmaxf(va.x + b.x, 0.f); va.y = fmaxf(va.y + b.y, 0.f);
      va.z = fmaxf(va.z + b.z, 0.f); va.w = fmaxf(va.w + b.w, 0.f);
      b = *(const float4*)&bias[cB];
      vb.x = fmaxf(vb.x + b.x, 0.f); vb.y = fmaxf(vb.y + b.y, 0.f);
      vb.z = fmaxf(vb.z + b.z, 0.f); vb.w = fmaxf(vb.w + b.w, 0.f);
    }
    *(float4*)&C[gr * FD + cA] = va;
    *(float4*)&C[gr * FD + cB] = vb;
  }
}

// ---------------- aggregation: out[c] = sum_in norm*hw[src] + dinv[c]^2*hw[c] + b ----------------
__global__ __launch_bounds__(256) void agg_kernel(const float* __restrict__ hw, float* __restrict__ out,
    const int* __restrict__ indptr, const int* __restrict__ csr_src, const float* __restrict__ csr_norm,
    const float* __restrict__ dinv, const float* __restrict__ bias, int n)
{
  int wave = (int)((blockIdx.x * blockDim.x + threadIdx.x) >> 6);
  int lane = threadIdx.x & 63;
  int nwaves = (int)((gridDim.x * blockDim.x) >> 6);
  float2 b2 = ((const float2*)bias)[lane];
  for (int c = wave; c < n; c += nwaves) {
    float di = dinv[c];
    float self = di * di;
    float2 h0 = ((const float2*)&hw[(size_t)c * FD])[lane];
    float ax = self * h0.x + b2.x;
    float ay = self * h0.y + b2.y;
    int e0 = indptr[c], e1 = indptr[c + 1];
    for (int e = e0; e < e1; ++e) {
      int s = csr_src[e];
      float w = csr_norm[e];
      float2 hv = ((const float2*)&hw[(size_t)s * FD])[lane];
      ax += w * hv.x;
      ay += w * hv.y;
    }
    float2 o; o.x = ax; o.y = ay;
    ((float2*)&out[(size_t)c * FD])[lane] = o;
  }
}

// ---------------- GraphNorm stats ----------------
__global__ void zero_stats(float* __restrict__ colsum, float* __restrict__ colsum2) {
  int t = threadIdx.x;
  if (t < FD) { colsum[t] = 0.f; colsum2[t] = 0.f; }
}

__global__ __launch_bounds__(256) void stats_kernel(const float* __restrict__ h, int n,
    float* __restrict__ colsum, float* __restrict__ colsum2)
{
  int t = threadIdx.x;
  int dq = t & 31;   // col quad: cols dq*4..dq*4+3
  int rg = t >> 5;   // 0..7
  float4 s = make_float4(0.f, 0.f, 0.f, 0.f);
  float4 s2 = make_float4(0.f, 0.f, 0.f, 0.f);
  for (int r = blockIdx.x * 8 + rg; r < n; r += gridDim.x * 8) {
    float4 v = *(const float4*)&h[(size_t)r * FD + dq * 4];
    s.x += v.x; s.y += v.y; s.z += v.z; s.w += v.w;
    s2.x += v.x * v.x; s2.y += v.y * v.y; s2.z += v.z * v.z; s2.w += v.w * v.w;
  }
  __shared__ float4 red[256];
  __shared__ float4 red2[256];
  red[t] = s; red2[t] = s2;
  __syncthreads();
  for (int off = 128; off >= 32; off >>= 1) {
    if (t < off) {
      float4 a = red[t + off];
      red[t].x += a.x; red[t].y += a.y; red[t].z += a.z; red[t].w += a.w;
      float4 b = red2[t + off];
      red2[t].x += b.x; red2[t].y += b.y; red2[t].z += b.z; red2[t].w += b.w;
    }
    __syncthreads();
  }
  if (t < 32) {
    float4 a = red[t], b = red2[t];
    atomicAdd(&colsum[t * 4 + 0], a.x); atomicAdd(&colsum[t * 4 + 1], a.y);
    atomicAdd(&colsum[t * 4 + 2], a.z); atomicAdd(&colsum[t * 4 + 3], a.w);
    atomicAdd(&colsum2[t * 4 + 0], b.x); atomicAdd(&colsum2[t * 4 + 1], b.y);
    atomicAdd(&colsum2[t * 4 + 2], b.z); atomicAdd(&colsum2[t * 4 + 3], b.w);
  }
}

__global__ void finalize_stats(const float* __restrict__ colsum, const float* __restrict__ colsum2,
    const float* __restrict__ gnw, const float* __restrict__ gnb, const float* __restrict__ ms,
    float* __restrict__ sv, float* __restrict__ tv, float inv_n)
{
  int d = threadIdx.x;
  if (d < FD) {
    float mean = colsum[d] * inv_n;
    float m2 = colsum2[d] * inv_n;
    float m = ms[d];
    float var = m2 - 2.f * m * mean * mean + m * m * mean * mean;
    float s = gnw[d] * rsqrtf(var + 1e-5f);
    sv[d] = s;
    tv[d] = gnb[d] - m * mean * s;
  }
}

// ---------------- apply (layers 1,2): x_next = relu(agg*s+t) + resid ----------------
__global__ __launch_bounds__(256) void apply_kernel(const float* __restrict__ agg, const float* __restrict__ resid,
    const float* __restrict__ sv, const float* __restrict__ tv, float* __restrict__ out, int total4)
{
  int i = blockIdx.x * blockDim.x + threadIdx.x;
  int stride = gridDim.x * blockDim.x;
  for (; i < total4; i += stride) {
    int d4 = i & 31;
    float4 a = ((const float4*)agg)[i];
    float4 r = ((const float4*)resid)[i];
    float4 s = ((const float4*)sv)[d4];
    float4 t = ((const float4*)tv)[d4];
    float4 o;
    o.x = fmaxf(a.x * s.x + t.x, 0.f) + r.x;
    o.y = fmaxf(a.y * s.y + t.y, 0.f) + r.y;
    o.z = fmaxf(a.z * s.z + t.z, 0.f) + r.z;
    o.w = fmaxf(a.w * s.w + t.w, 0.f) + r.w;
    ((float4*)out)[i] = o;
  }
}

// ---------------- head dot: out[r] = mlp_out[r] . head_w + head_b ----------------
__global__ __launch_bounds__(256) void headdot_kernel(const float* __restrict__ x, const float* __restrict__ hw,
    const float* __restrict__ hb, float* __restrict__ out, int n)
{
  int lane = threadIdx.x & 63;
  int wave = (int)((blockIdx.x * blockDim.x + threadIdx.x) >> 6);
  int nw = (int)((gridDim.x * blockDim.x) >> 6);
  float2 w2 = ((const float2*)hw)[lane];
  float b = hb[0];
  for (int r = wave; r < n; r += nw) {
    float2 v = ((const float2*)&x[(size_t)r * FD])[lane];
    float p = v.x * w2.x + v.y * w2.y;
    #pragma unroll
    for (int off = 32; off; off >>= 1) p += __shfl_xor(p, off);
    if (lane == 0) out[r] = p + b;
  }
}

// ---------------- launcher ----------------
extern "C" void kernel_launch(void* const* d_in, const int* in_sizes, int n_in,
                              void* d_out, int out_size, void* d_ws, size_t ws_size,
                              hipStream_t stream) {
  const float* x0      = (const float*)d_in[0];
  const int* ei        = (const int*)d_in[1];   // int32: harness converts integer inputs
  const float* conv_w  = (const float*)d_in[2];
  const float* conv_b  = (const float*)d_in[3];
  const float* gn_w    = (const float*)d_in[4];
  const float* gn_b    = (const float*)d_in[5];
  const float* gn_ms   = (const float*)d_in[6];
  const float* proj_w  = (const float*)d_in[7];
  const float* mlp_w   = (const float*)d_in[8];
  const float* mlp_b   = (const float*)d_in[9];
  const float* head_w  = (const float*)d_in[10];
  const float* head_b  = (const float*)d_in[11];
  float* out = (float*)d_out;

  const int n = in_sizes[0] / FD;
  const int e = in_sizes[1] / 2;
  const size_t ND = (size_t)n * FD;

  float* bufA     = (float*)d_ws;
  float* bufB     = bufA + ND;
  float* bufC     = bufB + ND;
  float* csr_norm = bufC + ND;
  float* dinv     = csr_norm + e;
  float* colsum   = dinv + n;
  float* colsum2  = colsum + FD;
  float* sv       = colsum2 + FD;
  float* tv       = sv + FD;
  int* deg     = (int*)(tv + FD);
  int* fill    = deg + n;
  int* indptr  = fill + n;
  int* tmp     = indptr + (n + 1);
  int* partials= tmp + n;
  int* csr_src = partials + 1024;

  const int nb256_n = (n + 255) / 256;
  const int nb256_e = (e + 255) / 256;
  const int nb128_n = (n + 127) / 128;

  // ---- graph preprocessing (rebuilt every call; no cached state) ----
  init_kernel<<<nb256_n, 256, 0, stream>>>(deg, fill, n);
  edge_count_kernel<<<nb256_e, 256, 0, stream>>>(ei, e, deg);
  dinv_kernel<<<nb256_n, 256, 0, stream>>>(deg, dinv, n);
  scan1_kernel<<<nb128_n, 128, 0, stream>>>(deg, n, tmp, partials);
  scan2_kernel<<<1, 1024, 0, stream>>>(partials, nb128_n);
  scan3_kernel<<<nb128_n, 128, 0, stream>>>(tmp, partials, indptr, n);
  fill_kernel<<<nb256_e, 256, 0, stream>>>(ei, e, indptr, fill, dinv, csr_src, csr_norm);

  const int gemm_grid = (n + 63) / 64;
  const float inv_n = 1.f / (float)n;
  const int total4 = (int)(ND / 4);

  // ---- layer 0 ----
  gemm128<0><<<gemm_grid, 256, 0, stream>>>(x0, conv_w + 0 * FD * FD, bufA, n, nullptr, nullptr, nullptr, nullptr);
  agg_kernel<<<2048, 256, 0, stream>>>(bufA, bufB, indptr, csr_src, csr_norm, dinv, conv_b + 0 * FD, n);
  zero_stats<<<1, 128, 0, stream>>>(colsum, colsum2);
  stats_kernel<<<256, 256, 0, stream>>>(bufB, n, colsum, colsum2);
  finalize_stats<<<1, 128, 0, stream>>>(colsum, colsum2, gn_w + 0 * FD, gn_b + 0 * FD, gn_ms + 0 * FD, sv, tv, inv_n);
  // x1 = relu(norm(agg)) + x0 @ proj_w   -> bufC
  gemm128<1><<<gemm_grid, 256, 0, stream>>>(x0, proj_w, bufC, n, bufB, sv, tv, nullptr);

  // ---- layer 1 ----
  gemm128<0><<<gemm_grid, 256, 0, stream>>>(bufC, conv_w + 1 * FD * FD, bufA, n, nullptr, nullptr, nullptr, nullptr);
  agg_kernel<<<2048, 256, 0, stream>>>(bufA, bufB, indptr, csr_src, csr_norm, dinv, conv_b + 1 * FD, n);
  zero_stats<<<1, 128, 0, stream>>>(colsum, colsum2);
  stats_kernel<<<256, 256, 0, stream>>>(bufB, n, colsum, colsum2);
  finalize_stats<<<1, 128, 0, stream>>>(colsum, colsum2, gn_w + 1 * FD, gn_b + 1 * FD, gn_ms + 1 * FD, sv, tv, inv_n);
  // x2 = relu(norm(agg)) + x1  -> bufA (HW1 dead)
  apply_kernel<<<2048, 256, 0, stream>>>(bufB, bufC, sv, tv, bufA, total4);

  // ---- layer 2 ----
  gemm128<0><<<gemm_grid, 256, 0, stream>>>(bufA, conv_w + 2 * FD * FD, bufC, n, nullptr, nullptr, nullptr, nullptr);
  agg_kernel<<<2048, 256, 0, stream>>>(bufC, bufB, indptr, csr_src, csr_norm, dinv, conv_b + 2 * FD, n);
  zero_stats<<<1, 128, 0, stream>>>(colsum, colsum2);
  stats_kernel<<<256, 256, 0, stream>>>(bufB, n, colsum, colsum2);
  finalize_stats<<<1, 128, 0, stream>>>(colsum, colsum2, gn_w + 2 * FD, gn_b + 2 * FD, gn_ms + 2 * FD, sv, tv, inv_n);
  // x3 = relu(norm(agg)) + x2  -> bufC (HW2 dead)
  apply_kernel<<<2048, 256, 0, stream>>>(bufB, bufA, sv, tv, bufC, total4);

  // ---- MLP + head ----
  gemm128<2><<<gemm_grid, 256, 0, stream>>>(bufC, mlp_w, bufA, n, nullptr, nullptr, nullptr, mlp_b);
  headdot_kernel<<<2048, 256, 0, stream>>>(bufA, head_w, head_b, out, n);
}

// Round 3
// 531.151 us; speedup vs baseline: 1.4275x; 1.4275x over previous
//
#include <hip/hip_runtime.h>

#define FD 128

typedef __attribute__((ext_vector_type(8))) short bf16x8;
typedef __attribute__((ext_vector_type(4))) float f32x4;

__device__ __forceinline__ unsigned short f2bf(float f) {
  unsigned int u = __float_as_uint(f);
  unsigned int r = (u + 0x7fffu + ((u >> 16) & 1u)) >> 16;
  return (unsigned short)r;
}
__device__ __forceinline__ float bf_lo(unsigned int u) { return __uint_as_float(u << 16); }
__device__ __forceinline__ float bf_hi(unsigned int u) { return __uint_as_float(u & 0xffff0000u); }
__device__ __forceinline__ unsigned int pack_bf2(float a, float b) {
  return (unsigned int)f2bf(a) | ((unsigned int)f2bf(b) << 16);
}
__device__ __forceinline__ float bf2f_us(unsigned short s) { return __uint_as_float(((unsigned int)s) << 16); }

// ---------------- graph preprocessing ----------------
__global__ __launch_bounds__(256) void init_kernel(int* __restrict__ deg, int* __restrict__ fill, int n) {
  int i = blockIdx.x * 256 + threadIdx.x;
  if (i < n) { deg[i] = 1; fill[i] = 0; }
}

__global__ __launch_bounds__(256) void edge_count_kernel(const int* __restrict__ ei, int e, int* __restrict__ deg) {
  int i = blockIdx.x * 256 + threadIdx.x;
  if (i < e) atomicAdd(&deg[ei[e + i]], 1);
}

__global__ __launch_bounds__(256) void dinv_kernel(const int* __restrict__ deg, float* __restrict__ dinv, int n) {
  int i = blockIdx.x * 256 + threadIdx.x;
  if (i < n) dinv[i] = rsqrtf((float)deg[i]);
}

__global__ __launch_bounds__(128) void scan1_kernel(const int* __restrict__ deg, int n, int* __restrict__ tmp, int* __restrict__ partials) {
  __shared__ int s[128];
  int b = blockIdx.x, t = threadIdx.x;
  int i = b * 128 + t;
  s[t] = (i < n) ? (deg[i] - 1) : 0;
  __syncthreads();
  for (int off = 1; off < 128; off <<= 1) {
    int u = (t >= off) ? s[t - off] : 0;
    __syncthreads();
    s[t] += u;
    __syncthreads();
  }
  if (i < n) tmp[i] = s[t];
  if (t == 127) partials[b] = s[127];
}

__global__ __launch_bounds__(1024) void scan2_kernel(int* __restrict__ partials, int nb) {
  __shared__ int s[1024];
  int t = threadIdx.x;
  s[t] = (t < nb) ? partials[t] : 0;
  __syncthreads();
  for (int off = 1; off < 1024; off <<= 1) {
    int u = (t >= off) ? s[t - off] : 0;
    __syncthreads();
    s[t] += u;
    __syncthreads();
  }
  if (t < nb) partials[t] = (t == 0) ? 0 : s[t - 1];
}

__global__ __launch_bounds__(128) void scan3_kernel(const int* __restrict__ tmp, const int* __restrict__ partials, int* __restrict__ indptr, int n) {
  int i = blockIdx.x * 128 + threadIdx.x;
  if (i < n) indptr[i + 1] = tmp[i] + partials[blockIdx.x];
  if (i == 0) indptr[0] = 0;
}

__global__ __launch_bounds__(256) void fill_kernel(const int* __restrict__ ei, int e,
    const int* __restrict__ indptr, int* __restrict__ fill, const float* __restrict__ dinv,
    int* __restrict__ csr_src, float* __restrict__ csr_norm) {
  int i = blockIdx.x * 256 + threadIdx.x;
  if (i < e) {
    int r = ei[i];
    int c = ei[e + i];
    int pos = indptr[c] + atomicAdd(&fill[c], 1);
    csr_src[pos] = r;
    csr_norm[pos] = dinv[r] * dinv[c];
  }
}

// ---------------- weight prep: Wt[m][col][k] = W[m][k][col] as bf16 ----------------
__global__ __launch_bounds__(256) void prep_w(const float* __restrict__ conv_w, const float* __restrict__ proj_w,
    const float* __restrict__ mlp_w, unsigned short* __restrict__ Wtb) {
  int idx = blockIdx.x * 256 + threadIdx.x;   // 5*16384 total
  int m = idx >> 14;
  int o = idx & 16383;
  int col = o >> 7, k = o & 127;
  const float* src = (m < 3) ? (conv_w + m * 16384) : ((m == 3) ? proj_w : mlp_w);
  Wtb[idx] = f2bf(src[k * FD + col]);
}

// ---------------- x0 f32 -> bf16 ----------------
__global__ __launch_bounds__(256) void convert_x0(const float* __restrict__ x, unsigned int* __restrict__ xb, int total2) {
  int i = blockIdx.x * blockDim.x + threadIdx.x;
  int stride = gridDim.x * blockDim.x;
  for (; i < total2; i += stride) {
    float2 v = ((const float2*)x)[i];
    xb[i] = pack_bf2(v.x, v.y);
  }
}

// ---------------- MFMA GEMM: C[n,128] = A[n,128]bf16 @ W[128,128] ----------------
// EPI 0: store bf16 A@W
// EPI 1: store bf16 relu(agg*s+t) + A@W        (layer-0 apply fused with proj GEMM)
// EPI 2: out[r] = relu(A@W + bias) . head_w + head_b   (MLP+head fused, f32 out)
template<int EPI>
__global__ __launch_bounds__(256) void mfma_gemm(const unsigned short* __restrict__ Ab,
    const unsigned short* __restrict__ Wtb, void* __restrict__ Cout, int n,
    const unsigned short* __restrict__ aggb, const float* __restrict__ sv, const float* __restrict__ tv,
    const float* __restrict__ bias, const float* __restrict__ hw, const float* __restrict__ hb)
{
  __shared__ uint4 bsh[2048];   // 32 KB, fragment-major: slot (nf*4+kf)*64 + lane
  const int tid = threadIdx.x;
  const int l = tid & 63;
  const int w = tid >> 6;
  const int row0 = blockIdx.x * 64 + w * 16;

  // stage Wt fragments (linear ds_write, conflict-free; W is L2-resident)
  #pragma unroll
  for (int it = 0; it < 8; ++it) {
    int s = it * 256 + tid;
    int nf = s >> 8, kf = (s >> 6) & 3, sl = s & 63;
    int col = nf * 16 + (sl & 15);
    bsh[s] = *(const uint4*)(Wtb + col * FD + kf * 32 + (sl >> 4) * 8);
  }

  // A fragments straight to registers: row = l&15, k = kf*32 + (l>>4)*8 + i
  int arow = row0 + (l & 15);
  bf16x8 a[4];
  if (arow < n) {
    const uint4* ap = (const uint4*)(Ab + (size_t)arow * FD + (l >> 4) * 8);
    #pragma unroll
    for (int kf = 0; kf < 4; ++kf) { uint4 t = ap[kf * 4]; a[kf] = *(bf16x8*)&t; }
  } else {
    #pragma unroll
    for (int kf = 0; kf < 4; ++kf) a[kf] = (bf16x8)(short)0;
  }

  __syncthreads();

  f32x4 acc[8];
  #pragma unroll
  for (int nf = 0; nf < 8; ++nf) acc[nf] = (f32x4)(0.0f);

  #pragma unroll
  for (int nf = 0; nf < 8; ++nf) {
    #pragma unroll
    for (int kf = 0; kf < 4; ++kf) {
      uint4 braw = bsh[(nf * 4 + kf) * 64 + l];
      acc[nf] = __builtin_amdgcn_mfma_f32_16x16x32_bf16(a[kf], *(bf16x8*)&braw, acc[nf], 0, 0, 0);
    }
  }

  // epilogue: C row = row0 + (l>>4)*4 + i, col = nf*16 + (l&15)
  if (EPI == 2) {
    float hsum[4] = {0.f, 0.f, 0.f, 0.f};
    #pragma unroll
    for (int nf = 0; nf < 8; ++nf) {
      int col = nf * 16 + (l & 15);
      float bm = bias[col];
      float hwc = hw[col];
      #pragma unroll
      for (int i = 0; i < 4; ++i)
        hsum[i] += fmaxf(acc[nf][i] + bm, 0.f) * hwc;
    }
    #pragma unroll
    for (int i = 0; i < 4; ++i) {
      #pragma unroll
      for (int off = 1; off < 16; off <<= 1) hsum[i] += __shfl_xor(hsum[i], off);
    }
    if ((l & 15) == 0) {
      float hb0 = hb[0];
      #pragma unroll
      for (int i = 0; i < 4; ++i) {
        int r = row0 + (l >> 4) * 4 + i;
        if (r < n) ((float*)Cout)[r] = hsum[i] + hb0;
      }
    }
  } else {
    unsigned short* outp = (unsigned short*)Cout;
    #pragma unroll
    for (int nf = 0; nf < 8; ++nf) {
      int col = nf * 16 + (l & 15);
      float s = (EPI == 1) ? sv[col] : 0.f;
      float t = (EPI == 1) ? tv[col] : 0.f;
      #pragma unroll
      for (int i = 0; i < 4; ++i) {
        int r = row0 + (l >> 4) * 4 + i;
        if (r < n) {
          float v = acc[nf][i];
          if (EPI == 1) {
            float ag = bf2f_us(aggb[(size_t)r * FD + col]);
            v += fmaxf(fmaf(ag, s, t), 0.f);
          }
          outp[(size_t)r * FD + col] = f2bf(v);
        }
      }
    }
  }
}

// ---------------- aggregation (bf16 rows) + fused GraphNorm stats ----------------
__global__ __launch_bounds__(256) void agg_bf16(const unsigned int* __restrict__ hw32, unsigned int* __restrict__ agg32,
    const int* __restrict__ indptr, const int* __restrict__ csr_src, const float* __restrict__ csr_norm,
    const float* __restrict__ dinv, const float* __restrict__ bias,
    float* __restrict__ colsum, float* __restrict__ colsum2, int n)
{
  __shared__ float sred[4][64][4];
  int wv = threadIdx.x >> 6;
  int lane = threadIdx.x & 63;
  int gw = blockIdx.x * 4 + wv;
  int nw = gridDim.x * 4;
  float2 b2 = ((const float2*)bias)[lane];
  float sx = 0.f, sy = 0.f, qx = 0.f, qy = 0.f;
  for (int c = gw; c < n; c += nw) {
    float di = dinv[c];
    float self = di * di;
    unsigned int su = hw32[(size_t)c * 64 + lane];
    float ax = self * bf_lo(su) + b2.x;
    float ay = self * bf_hi(su) + b2.y;
    int e0 = indptr[c], e1 = indptr[c + 1];
    for (int e = e0; e < e1; ++e) {
      int s = csr_src[e];
      float wn = csr_norm[e];
      unsigned int u = hw32[(size_t)s * 64 + lane];
      ax += wn * bf_lo(u);
      ay += wn * bf_hi(u);
    }
    agg32[(size_t)c * 64 + lane] = pack_bf2(ax, ay);
    sx += ax; sy += ay; qx += ax * ax; qy += ay * ay;
  }
  sred[wv][lane][0] = sx; sred[wv][lane][1] = sy;
  sred[wv][lane][2] = qx; sred[wv][lane][3] = qy;
  __syncthreads();
  int t = threadIdx.x;
  int cc = t & 127;
  int which = t >> 7;
  float v = 0.f;
  #pragma unroll
  for (int w2 = 0; w2 < 4; ++w2) v += sred[w2][cc >> 1][(which << 1) + (cc & 1)];
  atomicAdd(which ? &colsum2[cc] : &colsum[cc], v);
}

// ---------------- GraphNorm scalars ----------------
__global__ void zero_stats(float* __restrict__ colsum, float* __restrict__ colsum2) {
  int t = threadIdx.x;
  if (t < FD) { colsum[t] = 0.f; colsum2[t] = 0.f; }
}

__global__ void finalize_stats(const float* __restrict__ colsum, const float* __restrict__ colsum2,
    const float* __restrict__ gnw, const float* __restrict__ gnb, const float* __restrict__ ms,
    float* __restrict__ sv, float* __restrict__ tv, float inv_n)
{
  int d = threadIdx.x;
  if (d < FD) {
    float mean = colsum[d] * inv_n;
    float m2 = colsum2[d] * inv_n;
    float m = ms[d];
    float var = m2 - 2.f * m * mean * mean + m * m * mean * mean;
    float s = gnw[d] * rsqrtf(var + 1e-5f);
    sv[d] = s;
    tv[d] = gnb[d] - m * mean * s;
  }
}

// ---------------- apply (layers 1,2): x_next = relu(agg*s+t) + resid, all bf16 ----------------
__global__ __launch_bounds__(256) void apply_bf16(const uint4* __restrict__ aggb, const uint4* __restrict__ resid,
    const float* __restrict__ sv, const float* __restrict__ tv, uint4* __restrict__ outb, int total16)
{
  int i = blockIdx.x * blockDim.x + threadIdx.x;
  int stride = gridDim.x * blockDim.x;
  for (; i < total16; i += stride) {
    int d16 = i & 15;                 // which 8-col group within the row
    uint4 a = aggb[i];
    uint4 r = resid[i];
    float4 s0 = ((const float4*)sv)[d16 * 2];
    float4 s1 = ((const float4*)sv)[d16 * 2 + 1];
    float4 t0 = ((const float4*)tv)[d16 * 2];
    float4 t1 = ((const float4*)tv)[d16 * 2 + 1];
    uint4 o;
    o.x = pack_bf2(fmaxf(fmaf(bf_lo(a.x), s0.x, t0.x), 0.f) + bf_lo(r.x),
                   fmaxf(fmaf(bf_hi(a.x), s0.y, t0.y), 0.f) + bf_hi(r.x));
    o.y = pack_bf2(fmaxf(fmaf(bf_lo(a.y), s0.z, t0.z), 0.f) + bf_lo(r.y),
                   fmaxf(fmaf(bf_hi(a.y), s0.w, t0.w), 0.f) + bf_hi(r.y));
    o.z = pack_bf2(fmaxf(fmaf(bf_lo(a.z), s1.x, t1.x), 0.f) + bf_lo(r.z),
                   fmaxf(fmaf(bf_hi(a.z), s1.y, t1.y), 0.f) + bf_hi(r.z));
    o.w = pack_bf2(fmaxf(fmaf(bf_lo(a.w), s1.z, t1.z), 0.f) + bf_lo(r.w),
                   fmaxf(fmaf(bf_hi(a.w), s1.w, t1.w), 0.f) + bf_hi(r.w));
    outb[i] = o;
  }
}

// ---------------- launcher ----------------
extern "C" void kernel_launch(void* const* d_in, const int* in_sizes, int n_in,
                              void* d_out, int out_size, void* d_ws, size_t ws_size,
                              hipStream_t stream) {
  const float* x0      = (const float*)d_in[0];
  const int* ei        = (const int*)d_in[1];   // int32 per harness conversion
  const float* conv_w  = (const float*)d_in[2];
  const float* conv_b  = (const float*)d_in[3];
  const float* gn_w    = (const float*)d_in[4];
  const float* gn_b    = (const float*)d_in[5];
  const float* gn_ms   = (const float*)d_in[6];
  const float* proj_w  = (const float*)d_in[7];
  const float* mlp_w   = (const float*)d_in[8];
  const float* mlp_b   = (const float*)d_in[9];
  const float* head_w  = (const float*)d_in[10];
  const float* head_b  = (const float*)d_in[11];
  float* out = (float*)d_out;

  const int n = in_sizes[0] / FD;
  const int e = in_sizes[1] / 2;
  const size_t ND = (size_t)n * FD;

  unsigned short* xb0  = (unsigned short*)d_ws;
  unsigned short* xb1  = xb0 + ND;
  unsigned short* hwb  = xb1 + ND;
  unsigned short* aggb = hwb + ND;
  unsigned short* Wtb  = aggb + ND;          // 5 * 16384 bf16
  float* csr_norm = (float*)(Wtb + 5 * 16384);
  float* dinv     = csr_norm + e;
  float* colsum   = dinv + n;
  float* colsum2  = colsum + FD;
  float* sv       = colsum2 + FD;
  float* tv       = sv + FD;
  int* deg     = (int*)(tv + FD);
  int* fill    = deg + n;
  int* indptr  = fill + n;
  int* tmp     = indptr + (n + 1);
  int* partials= tmp + n;
  int* csr_src = partials + 1024;

  const int nb256_n = (n + 255) / 256;
  const int nb256_e = (e + 255) / 256;
  const int nb128_n = (n + 127) / 128;

  // ---- graph preprocessing ----
  init_kernel<<<nb256_n, 256, 0, stream>>>(deg, fill, n);
  edge_count_kernel<<<nb256_e, 256, 0, stream>>>(ei, e, deg);
  dinv_kernel<<<nb256_n, 256, 0, stream>>>(deg, dinv, n);
  scan1_kernel<<<nb128_n, 128, 0, stream>>>(deg, n, tmp, partials);
  scan2_kernel<<<1, 1024, 0, stream>>>(partials, nb128_n);
  scan3_kernel<<<nb128_n, 128, 0, stream>>>(tmp, partials, indptr, n);
  fill_kernel<<<nb256_e, 256, 0, stream>>>(ei, e, indptr, fill, dinv, csr_src, csr_norm);

  // ---- bf16 prep ----
  prep_w<<<320, 256, 0, stream>>>(conv_w, proj_w, mlp_w, Wtb);
  convert_x0<<<2048, 256, 0, stream>>>(x0, (unsigned int*)xb0, (int)(ND / 2));

  const int gemm_grid = (n + 63) / 64;
  const float inv_n = 1.f / (float)n;
  const int total16 = (int)(ND / 8);
  const unsigned short* Wt_conv0 = Wtb;
  const unsigned short* Wt_conv1 = Wtb + 16384;
  const unsigned short* Wt_conv2 = Wtb + 2 * 16384;
  const unsigned short* Wt_proj  = Wtb + 3 * 16384;
  const unsigned short* Wt_mlp   = Wtb + 4 * 16384;

  // ---- layer 0 ----
  mfma_gemm<0><<<gemm_grid, 256, 0, stream>>>(xb0, Wt_conv0, hwb, n, nullptr, nullptr, nullptr, nullptr, nullptr, nullptr);
  zero_stats<<<1, 128, 0, stream>>>(colsum, colsum2);
  agg_bf16<<<2048, 256, 0, stream>>>((const unsigned int*)hwb, (unsigned int*)aggb, indptr, csr_src, csr_norm, dinv,
                                     conv_b + 0 * FD, colsum, colsum2, n);
  finalize_stats<<<1, 128, 0, stream>>>(colsum, colsum2, gn_w + 0 * FD, gn_b + 0 * FD, gn_ms + 0 * FD, sv, tv, inv_n);
  mfma_gemm<1><<<gemm_grid, 256, 0, stream>>>(xb0, Wt_proj, xb1, n, aggb, sv, tv, nullptr, nullptr, nullptr);

  // ---- layer 1 ----
  mfma_gemm<0><<<gemm_grid, 256, 0, stream>>>(xb1, Wt_conv1, hwb, n, nullptr, nullptr, nullptr, nullptr, nullptr, nullptr);
  zero_stats<<<1, 128, 0, stream>>>(colsum, colsum2);
  agg_bf16<<<2048, 256, 0, stream>>>((const unsigned int*)hwb, (unsigned int*)aggb, indptr, csr_src, csr_norm, dinv,
                                     conv_b + 1 * FD, colsum, colsum2, n);
  finalize_stats<<<1, 128, 0, stream>>>(colsum, colsum2, gn_w + 1 * FD, gn_b + 1 * FD, gn_ms + 1 * FD, sv, tv, inv_n);
  apply_bf16<<<2048, 256, 0, stream>>>((const uint4*)aggb, (const uint4*)xb1, sv, tv, (uint4*)xb0, total16);

  // ---- layer 2 ----
  mfma_gemm<0><<<gemm_grid, 256, 0, stream>>>(xb0, Wt_conv2, hwb, n, nullptr, nullptr, nullptr, nullptr, nullptr, nullptr);
  zero_stats<<<1, 128, 0, stream>>>(colsum, colsum2);
  agg_bf16<<<2048, 256, 0, stream>>>((const unsigned int*)hwb, (unsigned int*)aggb, indptr, csr_src, csr_norm, dinv,
                                     conv_b + 2 * FD, colsum, colsum2, n);
  finalize_stats<<<1, 128, 0, stream>>>(colsum, colsum2, gn_w + 2 * FD, gn_b + 2 * FD, gn_ms + 2 * FD, sv, tv, inv_n);
  apply_bf16<<<2048, 256, 0, stream>>>((const uint4*)aggb, (const uint4*)xb0, sv, tv, (uint4*)xb1, total16);

  // ---- MLP + head (fused) ----
  mfma_gemm<2><<<gemm_grid, 256, 0, stream>>>(xb1, Wt_mlp, out, n, nullptr, nullptr, nullptr, mlp_b, head_w, head_b);
}

// Round 5
// 446.136 us; speedup vs baseline: 1.6995x; 1.1906x over previous
//
#include <hip/hip_runtime.h>

#define FD 128

typedef __attribute__((ext_vector_type(8))) short bf16x8;
typedef __attribute__((ext_vector_type(4))) float f32x4;

__device__ __forceinline__ unsigned short f2bf(float f) {
  unsigned int u = __float_as_uint(f);
  unsigned int r = (u + 0x7fffu + ((u >> 16) & 1u)) >> 16;
  return (unsigned short)r;
}
__device__ __forceinline__ float bf_lo(unsigned int u) { return __uint_as_float(u << 16); }
__device__ __forceinline__ float bf_hi(unsigned int u) { return __uint_as_float(u & 0xffff0000u); }
__device__ __forceinline__ unsigned int pack_bf2(float a, float b) {
  return (unsigned int)f2bf(a) | ((unsigned int)f2bf(b) << 16);
}
__device__ __forceinline__ float bf2f_us(unsigned short s) { return __uint_as_float(((unsigned int)s) << 16); }

// ---------------- graph preprocessing ----------------
__global__ __launch_bounds__(256) void init_kernel(int* __restrict__ deg, int* __restrict__ fill,
    float* __restrict__ stats, int n) {
  int i = blockIdx.x * 256 + threadIdx.x;
  if (i < n) { deg[i] = 1; fill[i] = 0; }
  if (i < 768) stats[i] = 0.f;   // colsum[3][128] + colsum2[3][128]
}

__global__ __launch_bounds__(256) void edge_count_kernel(const int* __restrict__ ei, int e, int* __restrict__ deg) {
  int i = blockIdx.x * 256 + threadIdx.x;
  if (i < e) atomicAdd(&deg[ei[e + i]], 1);
}

// scan over (deg-1) to get CSR edge offsets; also emits dinv = rsqrt(deg)
__global__ __launch_bounds__(128) void scan1_kernel(const int* __restrict__ deg, int n,
    int* __restrict__ tmp, int* __restrict__ partials, float* __restrict__ dinv) {
  __shared__ int s[128];
  int b = blockIdx.x, t = threadIdx.x;
  int i = b * 128 + t;
  int d = (i < n) ? deg[i] : 1;
  if (i < n) dinv[i] = rsqrtf((float)d);
  s[t] = (i < n) ? (d - 1) : 0;
  __syncthreads();
  for (int off = 1; off < 128; off <<= 1) {
    int u = (t >= off) ? s[t - off] : 0;
    __syncthreads();
    s[t] += u;
    __syncthreads();
  }
  if (i < n) tmp[i] = s[t];
  if (t == 127) partials[b] = s[127];
}

__global__ __launch_bounds__(1024) void scan2_kernel(int* __restrict__ partials, int nb) {
  __shared__ int s[1024];
  int t = threadIdx.x;
  s[t] = (t < nb) ? partials[t] : 0;
  __syncthreads();
  for (int off = 1; off < 1024; off <<= 1) {
    int u = (t >= off) ? s[t - off] : 0;
    __syncthreads();
    s[t] += u;
    __syncthreads();
  }
  if (t < nb) partials[t] = (t == 0) ? 0 : s[t - 1];
}

__global__ __launch_bounds__(128) void scan3_kernel(const int* __restrict__ tmp, const int* __restrict__ partials, int* __restrict__ indptr, int n) {
  int i = blockIdx.x * 128 + threadIdx.x;
  if (i < n) indptr[i + 1] = tmp[i] + partials[blockIdx.x];
  if (i == 0) indptr[0] = 0;
}

__global__ __launch_bounds__(256) void fill_kernel(const int* __restrict__ ei, int e,
    const int* __restrict__ indptr, int* __restrict__ fill, const float* __restrict__ dinv,
    int* __restrict__ csr_src, float* __restrict__ csr_norm) {
  int i = blockIdx.x * 256 + threadIdx.x;
  if (i < e) {
    int r = ei[i];
    int c = ei[e + i];
    int pos = indptr[c] + atomicAdd(&fill[c], 1);
    csr_src[pos] = r;
    csr_norm[pos] = dinv[r] * dinv[c];
  }
}

// ---------------- weight prep: Wt[m][col][k] = W[m][k][col] as bf16 ----------------
__global__ __launch_bounds__(256) void prep_w(const float* __restrict__ conv_w, const float* __restrict__ proj_w,
    const float* __restrict__ mlp_w, unsigned short* __restrict__ Wtb) {
  int idx = blockIdx.x * 256 + threadIdx.x;   // 5*16384 total
  int m = idx >> 14;
  int o = idx & 16383;
  int col = o >> 7, k = o & 127;
  const float* src = (m < 3) ? (conv_w + m * 16384) : ((m == 3) ? proj_w : mlp_w);
  Wtb[idx] = f2bf(src[k * FD + col]);
}

// ---------------- x0 f32 -> bf16 ----------------
__global__ __launch_bounds__(256) void convert_x0(const float* __restrict__ x, unsigned int* __restrict__ xb, int total2) {
  int i = blockIdx.x * blockDim.x + threadIdx.x;
  int stride = gridDim.x * blockDim.x;
  for (; i < total2; i += stride) {
    float2 v = ((const float2*)x)[i];
    xb[i] = pack_bf2(v.x, v.y);
  }
}

// ---------------- MFMA GEMM: C[n,128] = A[n,128]bf16 @ W[128,128] ----------------
// EPI 0: store bf16 A@W
// EPI 1: store bf16 relu(agg*s+t) + A@W        (layer-0 apply fused with proj GEMM)
// EPI 2: out[r] = relu(A@W + bias) . head_w + head_b   (MLP+head fused, f32 out)
template<int EPI>
__global__ __launch_bounds__(256) void mfma_gemm(const unsigned short* __restrict__ Ab,
    const unsigned short* __restrict__ Wtb, void* __restrict__ Cout, int n,
    const unsigned short* __restrict__ aggb, const float* __restrict__ sv, const float* __restrict__ tv,
    const float* __restrict__ bias, const float* __restrict__ hw, const float* __restrict__ hb)
{
  __shared__ uint4 bsh[2048];   // 32 KB, fragment-major: slot (nf*4+kf)*64 + lane
  const int tid = threadIdx.x;
  const int l = tid & 63;
  const int w = tid >> 6;
  const int row0 = blockIdx.x * 64 + w * 16;

  // stage Wt fragments (linear ds_write, conflict-free; W is L2-resident)
  #pragma unroll
  for (int it = 0; it < 8; ++it) {
    int s = it * 256 + tid;
    int nf = s >> 8, kf = (s >> 6) & 3, sl = s & 63;
    int col = nf * 16 + (sl & 15);
    bsh[s] = *(const uint4*)(Wtb + col * FD + kf * 32 + (sl >> 4) * 8);
  }

  // A fragments straight to registers: row = l&15, k = kf*32 + (l>>4)*8 + i
  int arow = row0 + (l & 15);
  bf16x8 a[4];
  if (arow < n) {
    const uint4* ap = (const uint4*)(Ab + (size_t)arow * FD + (l >> 4) * 8);
    #pragma unroll
    for (int kf = 0; kf < 4; ++kf) { uint4 t = ap[kf * 4]; a[kf] = *(bf16x8*)&t; }
  } else {
    #pragma unroll
    for (int kf = 0; kf < 4; ++kf) a[kf] = (bf16x8)(short)0;
  }

  __syncthreads();

  f32x4 acc[8];
  #pragma unroll
  for (int nf = 0; nf < 8; ++nf) acc[nf] = (f32x4)(0.0f);

  #pragma unroll
  for (int nf = 0; nf < 8; ++nf) {
    #pragma unroll
    for (int kf = 0; kf < 4; ++kf) {
      uint4 braw = bsh[(nf * 4 + kf) * 64 + l];
      acc[nf] = __builtin_amdgcn_mfma_f32_16x16x32_bf16(a[kf], *(bf16x8*)&braw, acc[nf], 0, 0, 0);
    }
  }

  // epilogue: C row = row0 + (l>>4)*4 + i, col = nf*16 + (l&15)
  if (EPI == 2) {
    float hsum[4] = {0.f, 0.f, 0.f, 0.f};
    #pragma unroll
    for (int nf = 0; nf < 8; ++nf) {
      int col = nf * 16 + (l & 15);
      float bm = bias[col];
      float hwc = hw[col];
      #pragma unroll
      for (int i = 0; i < 4; ++i)
        hsum[i] += fmaxf(acc[nf][i] + bm, 0.f) * hwc;
    }
    #pragma unroll
    for (int i = 0; i < 4; ++i) {
      #pragma unroll
      for (int off = 1; off < 16; off <<= 1) hsum[i] += __shfl_xor(hsum[i], off);
    }
    if ((l & 15) == 0) {
      float hb0 = hb[0];
      #pragma unroll
      for (int i = 0; i < 4; ++i) {
        int r = row0 + (l >> 4) * 4 + i;
        if (r < n) ((float*)Cout)[r] = hsum[i] + hb0;
      }
    }
  } else {
    unsigned short* outp = (unsigned short*)Cout;
    #pragma unroll
    for (int nf = 0; nf < 8; ++nf) {
      int col = nf * 16 + (l & 15);
      float s = (EPI == 1) ? sv[col] : 0.f;
      float t = (EPI == 1) ? tv[col] : 0.f;
      #pragma unroll
      for (int i = 0; i < 4; ++i) {
        int r = row0 + (l >> 4) * 4 + i;
        if (r < n) {
          float v = acc[nf][i];
          if (EPI == 1) {
            float ag = bf2f_us(aggb[(size_t)r * FD + col]);
            v += fmaxf(fmaf(ag, s, t), 0.f);
          }
          outp[(size_t)r * FD + col] = f2bf(v);
        }
      }
    }
  }
}

// ---------------- aggregation (bf16 rows) + fused GraphNorm stats ----------------
// 2 rows per wave (32 lanes x uint2 = 8B/lane = 4 bf16 cols), edge loop unrolled x4:
// up to 8 outstanding gathers per wave to hide L2/L3 latency.
__global__ __launch_bounds__(256) void agg_bf16(const uint2* __restrict__ hw2, uint2* __restrict__ agg2,
    const int* __restrict__ indptr, const int* __restrict__ csr_src, const float* __restrict__ csr_norm,
    const float* __restrict__ dinv, const float* __restrict__ bias,
    float* __restrict__ colsum, float* __restrict__ colsum2, int n)
{
  __shared__ float sredS[4][2][32][4];
  __shared__ float sredQ[4][2][32][4];
  const int wv = threadIdx.x >> 6;
  const int lane = threadIdx.x & 63;
  const int half = lane >> 5;
  const int l32 = lane & 31;
  const int gw = blockIdx.x * 4 + wv;
  const int nw = gridDim.x * 4;
  const float4 b4 = ((const float4*)bias)[l32];
  float sx0 = 0.f, sx1 = 0.f, sx2 = 0.f, sx3 = 0.f;
  float q0 = 0.f, q1 = 0.f, q2 = 0.f, q3 = 0.f;

  for (int c = gw * 2 + half; c < n; c += nw * 2) {
    float di = dinv[c];
    float self = di * di;
    uint2 su = hw2[(size_t)c * 32 + l32];
    float a0 = fmaf(self, bf_lo(su.x), b4.x);
    float a1 = fmaf(self, bf_hi(su.x), b4.y);
    float a2 = fmaf(self, bf_lo(su.y), b4.z);
    float a3 = fmaf(self, bf_hi(su.y), b4.w);
    int e = indptr[c], e1 = indptr[c + 1];
    for (; e + 4 <= e1; e += 4) {
      int s0 = csr_src[e], s1 = csr_src[e + 1], s2 = csr_src[e + 2], s3 = csr_src[e + 3];
      float w0 = csr_norm[e], w1 = csr_norm[e + 1], w2 = csr_norm[e + 2], w3 = csr_norm[e + 3];
      uint2 u0 = hw2[(size_t)s0 * 32 + l32];
      uint2 u1 = hw2[(size_t)s1 * 32 + l32];
      uint2 u2 = hw2[(size_t)s2 * 32 + l32];
      uint2 u3 = hw2[(size_t)s3 * 32 + l32];
      a0 = fmaf(w0, bf_lo(u0.x), a0); a1 = fmaf(w0, bf_hi(u0.x), a1);
      a2 = fmaf(w0, bf_lo(u0.y), a2); a3 = fmaf(w0, bf_hi(u0.y), a3);
      a0 = fmaf(w1, bf_lo(u1.x), a0); a1 = fmaf(w1, bf_hi(u1.x), a1);
      a2 = fmaf(w1, bf_lo(u1.y), a2); a3 = fmaf(w1, bf_hi(u1.y), a3);
      a0 = fmaf(w2, bf_lo(u2.x), a0); a1 = fmaf(w2, bf_hi(u2.x), a1);
      a2 = fmaf(w2, bf_lo(u2.y), a2); a3 = fmaf(w2, bf_hi(u2.y), a3);
      a0 = fmaf(w3, bf_lo(u3.x), a0); a1 = fmaf(w3, bf_hi(u3.x), a1);
      a2 = fmaf(w3, bf_lo(u3.y), a2); a3 = fmaf(w3, bf_hi(u3.y), a3);
    }
    for (; e < e1; ++e) {
      int s0 = csr_src[e];
      float w0 = csr_norm[e];
      uint2 u0 = hw2[(size_t)s0 * 32 + l32];
      a0 = fmaf(w0, bf_lo(u0.x), a0); a1 = fmaf(w0, bf_hi(u0.x), a1);
      a2 = fmaf(w0, bf_lo(u0.y), a2); a3 = fmaf(w0, bf_hi(u0.y), a3);
    }
    uint2 o; o.x = pack_bf2(a0, a1); o.y = pack_bf2(a2, a3);
    agg2[(size_t)c * 32 + l32] = o;
    sx0 += a0; sx1 += a1; sx2 += a2; sx3 += a3;
    q0 += a0 * a0; q1 += a1 * a1; q2 += a2 * a2; q3 += a3 * a3;
  }

  sredS[wv][half][l32][0] = sx0; sredS[wv][half][l32][1] = sx1;
  sredS[wv][half][l32][2] = sx2; sredS[wv][half][l32][3] = sx3;
  sredQ[wv][half][l32][0] = q0; sredQ[wv][half][l32][1] = q1;
  sredQ[wv][half][l32][2] = q2; sredQ[wv][half][l32][3] = q3;
  __syncthreads();
  int t = threadIdx.x;
  int which = t >> 7, cc = t & 127;
  int rl = cc >> 2, rk = cc & 3;
  float v = 0.f;
  #pragma unroll
  for (int w2 = 0; w2 < 4; ++w2)
    #pragma unroll
    for (int h = 0; h < 2; ++h)
      v += which ? sredQ[w2][h][rl][rk] : sredS[w2][h][rl][rk];
  atomicAdd(which ? &colsum2[cc] : &colsum[cc], v);
}

// ---------------- GraphNorm scalars ----------------
__global__ void finalize_stats(const float* __restrict__ colsum, const float* __restrict__ colsum2,
    const float* __restrict__ gnw, const float* __restrict__ gnb, const float* __restrict__ ms,
    float* __restrict__ sv, float* __restrict__ tv, float inv_n)
{
  int d = threadIdx.x;
  if (d < FD) {
    float mean = colsum[d] * inv_n;
    float m2 = colsum2[d] * inv_n;
    float m = ms[d];
    float var = m2 - 2.f * m * mean * mean + m * m * mean * mean;
    float s = gnw[d] * rsqrtf(var + 1e-5f);
    sv[d] = s;
    tv[d] = gnb[d] - m * mean * s;
  }
}

// ---------------- apply (layers 1,2): x_next = relu(agg*s+t) + resid, all bf16 ----------------
__global__ __launch_bounds__(256) void apply_bf16(const uint4* __restrict__ aggb, const uint4* __restrict__ resid,
    const float* __restrict__ sv, const float* __restrict__ tv, uint4* __restrict__ outb, int total16)
{
  int i = blockIdx.x * blockDim.x + threadIdx.x;
  int stride = gridDim.x * blockDim.x;
  for (; i < total16; i += stride) {
    int d16 = i & 15;                 // which 8-col group within the row
    uint4 a = aggb[i];
    uint4 r = resid[i];
    float4 s0 = ((const float4*)sv)[d16 * 2];
    float4 s1 = ((const float4*)sv)[d16 * 2 + 1];
    float4 t0 = ((const float4*)tv)[d16 * 2];
    float4 t1 = ((const float4*)tv)[d16 * 2 + 1];
    uint4 o;
    o.x = pack_bf2(fmaxf(fmaf(bf_lo(a.x), s0.x, t0.x), 0.f) + bf_lo(r.x),
                   fmaxf(fmaf(bf_hi(a.x), s0.y, t0.y), 0.f) + bf_hi(r.x));
    o.y = pack_bf2(fmaxf(fmaf(bf_lo(a.y), s0.z, t0.z), 0.f) + bf_lo(r.y),
                   fmaxf(fmaf(bf_hi(a.y), s0.w, t0.w), 0.f) + bf_hi(r.y));
    o.z = pack_bf2(fmaxf(fmaf(bf_lo(a.z), s1.x, t1.x), 0.f) + bf_lo(r.z),
                   fmaxf(fmaf(bf_hi(a.z), s1.y, t1.y), 0.f) + bf_hi(r.z));
    o.w = pack_bf2(fmaxf(fmaf(bf_lo(a.w), s1.z, t1.z), 0.f) + bf_lo(r.w),
                   fmaxf(fmaf(bf_hi(a.w), s1.w, t1.w), 0.f) + bf_hi(r.w));
    outb[i] = o;
  }
}

// ---------------- launcher ----------------
extern "C" void kernel_launch(void* const* d_in, const int* in_sizes, int n_in,
                              void* d_out, int out_size, void* d_ws, size_t ws_size,
                              hipStream_t stream) {
  const float* x0      = (const float*)d_in[0];
  const int* ei        = (const int*)d_in[1];   // int32 per harness conversion
  const float* conv_w  = (const float*)d_in[2];
  const float* conv_b  = (const float*)d_in[3];
  const float* gn_w    = (const float*)d_in[4];
  const float* gn_b    = (const float*)d_in[5];
  const float* gn_ms   = (const float*)d_in[6];
  const float* proj_w  = (const float*)d_in[7];
  const float* mlp_w   = (const float*)d_in[8];
  const float* mlp_b   = (const float*)d_in[9];
  const float* head_w  = (const float*)d_in[10];
  const float* head_b  = (const float*)d_in[11];
  float* out = (float*)d_out;

  const int n = in_sizes[0] / FD;
  const int e = in_sizes[1] / 2;
  const size_t ND = (size_t)n * FD;

  unsigned short* xb0  = (unsigned short*)d_ws;
  unsigned short* xb1  = xb0 + ND;
  unsigned short* hwb  = xb1 + ND;
  unsigned short* aggb = hwb + ND;
  unsigned short* Wtb  = aggb + ND;          // 5 * 16384 bf16
  float* csr_norm = (float*)(Wtb + 5 * 16384);
  float* dinv     = csr_norm + e;
  float* stats    = dinv + n;                // colsum[3][128] then colsum2[3][128]
  float* sv       = stats + 768;
  float* tv       = sv + FD;
  int* deg     = (int*)(tv + FD);
  int* fill    = deg + n;
  int* indptr  = fill + n;
  int* tmp     = indptr + (n + 1);
  int* partials= tmp + n;
  int* csr_src = partials + 1024;

  const int nb256_n = (n + 255) / 256;
  const int nb256_e = (e + 255) / 256;
  const int nb128_n = (n + 127) / 128;

  // ---- graph preprocessing ----
  init_kernel<<<nb256_n, 256, 0, stream>>>(deg, fill, stats, n);
  edge_count_kernel<<<nb256_e, 256, 0, stream>>>(ei, e, deg);
  scan1_kernel<<<nb128_n, 128, 0, stream>>>(deg, n, tmp, partials, dinv);
  scan2_kernel<<<1, 1024, 0, stream>>>(partials, nb128_n);
  scan3_kernel<<<nb128_n, 128, 0, stream>>>(tmp, partials, indptr, n);
  fill_kernel<<<nb256_e, 256, 0, stream>>>(ei, e, indptr, fill, dinv, csr_src, csr_norm);

  // ---- bf16 prep ----
  prep_w<<<320, 256, 0, stream>>>(conv_w, proj_w, mlp_w, Wtb);
  convert_x0<<<2048, 256, 0, stream>>>(x0, (unsigned int*)xb0, (int)(ND / 2));

  const int gemm_grid = (n + 63) / 64;
  const float inv_n = 1.f / (float)n;
  const int total16 = (int)(ND / 8);
  const unsigned short* Wt_conv0 = Wtb;
  const unsigned short* Wt_conv1 = Wtb + 16384;
  const unsigned short* Wt_conv2 = Wtb + 2 * 16384;
  const unsigned short* Wt_proj  = Wtb + 3 * 16384;
  const unsigned short* Wt_mlp   = Wtb + 4 * 16384;

  // ---- layer 0 ----
  mfma_gemm<0><<<gemm_grid, 256, 0, stream>>>(xb0, Wt_conv0, hwb, n, nullptr, nullptr, nullptr, nullptr, nullptr, nullptr);
  agg_bf16<<<2048, 256, 0, stream>>>((const uint2*)hwb, (uint2*)aggb, indptr, csr_src, csr_norm, dinv,
                                     conv_b + 0 * FD, stats + 0 * FD, stats + 384 + 0 * FD, n);
  finalize_stats<<<1, 128, 0, stream>>>(stats + 0 * FD, stats + 384 + 0 * FD, gn_w + 0 * FD, gn_b + 0 * FD, gn_ms + 0 * FD, sv, tv, inv_n);
  mfma_gemm<1><<<gemm_grid, 256, 0, stream>>>(xb0, Wt_proj, xb1, n, aggb, sv, tv, nullptr, nullptr, nullptr);

  // ---- layer 1 ----
  mfma_gemm<0><<<gemm_grid, 256, 0, stream>>>(xb1, Wt_conv1, hwb, n, nullptr, nullptr, nullptr, nullptr, nullptr, nullptr);
  agg_bf16<<<2048, 256, 0, stream>>>((const uint2*)hwb, (uint2*)aggb, indptr, csr_src, csr_norm, dinv,
                                     conv_b + 1 * FD, stats + 1 * FD, stats + 384 + 1 * FD, n);
  finalize_stats<<<1, 128, 0, stream>>>(stats + 1 * FD, stats + 384 + 1 * FD, gn_w + 1 * FD, gn_b + 1 * FD, gn_ms + 1 * FD, sv, tv, inv_n);
  apply_bf16<<<2048, 256, 0, stream>>>((const uint4*)aggb, (const uint4*)xb1, sv, tv, (uint4*)xb0, total16);

  // ---- layer 2 ----
  mfma_gemm<0><<<gemm_grid, 256, 0, stream>>>(xb0, Wt_conv2, hwb, n, nullptr, nullptr, nullptr, nullptr, nullptr, nullptr);
  agg_bf16<<<2048, 256, 0, stream>>>((const uint2*)hwb, (uint2*)aggb, indptr, csr_src, csr_norm, dinv,
                                     conv_b + 2 * FD, stats + 2 * FD, stats + 384 + 2 * FD, n);
  finalize_stats<<<1, 128, 0, stream>>>(stats + 2 * FD, stats + 384 + 2 * FD, gn_w + 2 * FD, gn_b + 2 * FD, gn_ms + 2 * FD, sv, tv, inv_n);
  apply_bf16<<<2048, 256, 0, stream>>>((const uint4*)aggb, (const uint4*)xb0, sv, tv, (uint4*)xb1, total16);

  // ---- MLP + head (fused) ----
  mfma_gemm<2><<<gemm_grid, 256, 0, stream>>>(xb1, Wt_mlp, out, n, nullptr, nullptr, nullptr, mlp_b, head_w, head_b);
}

// Round 7
// 419.650 us; speedup vs baseline: 1.8067x; 1.0631x over previous
//
#include <hip/hip_runtime.h>

#define FD 128

typedef __attribute__((ext_vector_type(8))) short bf16x8;
typedef __attribute__((ext_vector_type(4))) float f32x4;

__device__ __forceinline__ unsigned short f2bf(float f) {
  unsigned int u = __float_as_uint(f);
  unsigned int r = (u + 0x7fffu + ((u >> 16) & 1u)) >> 16;
  return (unsigned short)r;
}
__device__ __forceinline__ float bf_lo(unsigned int u) { return __uint_as_float(u << 16); }
__device__ __forceinline__ float bf_hi(unsigned int u) { return __uint_as_float(u & 0xffff0000u); }
__device__ __forceinline__ unsigned int pack_bf2(float a, float b) {
  return (unsigned int)f2bf(a) | ((unsigned int)f2bf(b) << 16);
}
__device__ __forceinline__ float bf2f_us(unsigned short s) { return __uint_as_float(((unsigned int)s) << 16); }

// ---------------- graph preprocessing ----------------
__global__ __launch_bounds__(256) void init_kernel(int* __restrict__ deg, int* __restrict__ fill,
    float* __restrict__ stats, int n) {
  int i = blockIdx.x * 256 + threadIdx.x;
  if (i < n) { deg[i] = 1; fill[i] = 0; }
  if (i < 768) stats[i] = 0.f;   // colsum[3][128] + colsum2[3][128]
}

__global__ __launch_bounds__(256) void edge_count_kernel(const int* __restrict__ ei, int e, int* __restrict__ deg) {
  int i = blockIdx.x * 256 + threadIdx.x;
  if (i < e) atomicAdd(&deg[ei[e + i]], 1);
}

// scan over (deg-1) to get CSR edge offsets; also emits dinv = rsqrt(deg)
__global__ __launch_bounds__(128) void scan1_kernel(const int* __restrict__ deg, int n,
    int* __restrict__ tmp, int* __restrict__ partials, float* __restrict__ dinv) {
  __shared__ int s[128];
  int b = blockIdx.x, t = threadIdx.x;
  int i = b * 128 + t;
  int d = (i < n) ? deg[i] : 1;
  if (i < n) dinv[i] = rsqrtf((float)d);
  s[t] = (i < n) ? (d - 1) : 0;
  __syncthreads();
  for (int off = 1; off < 128; off <<= 1) {
    int u = (t >= off) ? s[t - off] : 0;
    __syncthreads();
    s[t] += u;
    __syncthreads();
  }
  if (i < n) tmp[i] = s[t];
  if (t == 127) partials[b] = s[127];
}

__global__ __launch_bounds__(1024) void scan2_kernel(int* __restrict__ partials, int nb) {
  __shared__ int s[1024];
  int t = threadIdx.x;
  s[t] = (t < nb) ? partials[t] : 0;
  __syncthreads();
  for (int off = 1; off < 1024; off <<= 1) {
    int u = (t >= off) ? s[t - off] : 0;
    __syncthreads();
    s[t] += u;
    __syncthreads();
  }
  if (t < nb) partials[t] = (t == 0) ? 0 : s[t - 1];
}

__global__ __launch_bounds__(128) void scan3_kernel(const int* __restrict__ tmp, const int* __restrict__ partials, int* __restrict__ indptr, int n) {
  int i = blockIdx.x * 128 + threadIdx.x;
  if (i < n) indptr[i + 1] = tmp[i] + partials[blockIdx.x];
  if (i == 0) indptr[0] = 0;
}

__global__ __launch_bounds__(256) void fill_kernel(const int* __restrict__ ei, int e,
    const int* __restrict__ indptr, int* __restrict__ fill, const float* __restrict__ dinv,
    int* __restrict__ csr_src, float* __restrict__ csr_norm) {
  int i = blockIdx.x * 256 + threadIdx.x;
  if (i < e) {
    int r = ei[i];
    int c = ei[e + i];
    int pos = indptr[c] + atomicAdd(&fill[c], 1);
    csr_src[pos] = r;
    csr_norm[pos] = dinv[r] * dinv[c];
  }
}

// ---------------- weight prep: Wt[m][col][k] = W[m][k][col] as bf16 ----------------
__global__ __launch_bounds__(256) void prep_w(const float* __restrict__ conv_w, const float* __restrict__ proj_w,
    const float* __restrict__ mlp_w, unsigned short* __restrict__ Wtb) {
  int idx = blockIdx.x * 256 + threadIdx.x;   // 5*16384 total
  int m = idx >> 14;
  int o = idx & 16383;
  int col = o >> 7, k = o & 127;
  const float* src = (m < 3) ? (conv_w + m * 16384) : ((m == 3) ? proj_w : mlp_w);
  Wtb[idx] = f2bf(src[k * FD + col]);
}

// ---------------- x0 f32 -> bf16 ----------------
__global__ __launch_bounds__(256) void convert_x0(const float* __restrict__ x, unsigned int* __restrict__ xb, int total2) {
  int i = blockIdx.x * blockDim.x + threadIdx.x;
  int stride = gridDim.x * blockDim.x;
  for (; i < total2; i += stride) {
    float2 v = ((const float2*)x)[i];
    xb[i] = pack_bf2(v.x, v.y);
  }
}

// ---------------- MFMA GEMM: C[n,128] = A[n,128]bf16 @ W[128,128] ----------------
// EPI 0: store bf16 A@W
// EPI 1: store bf16 relu(agg*s+t) + A@W        (layer-0 apply fused with proj GEMM, epilogue side)
// EPI 2: out[r] = relu(A@W + bias) . head_w + head_b   (MLP+head fused, f32 out)
// FUSEA: A := relu(Ab*svA+tvA) + residA computed inline in the A-fragment loader;
//        if xout != nullptr the computed A rows are also written back (materializes x2).
template<int EPI, bool FUSEA>
__global__ __launch_bounds__(256) void mfma_gemm(const unsigned short* __restrict__ Ab,
    const unsigned short* __restrict__ Wtb, void* __restrict__ Cout, int n,
    const unsigned short* __restrict__ aggb, const float* __restrict__ sv, const float* __restrict__ tv,
    const float* __restrict__ bias, const float* __restrict__ hw, const float* __restrict__ hb,
    const float* __restrict__ svA, const float* __restrict__ tvA,
    const unsigned short* __restrict__ residA, unsigned short* __restrict__ xout)
{
  __shared__ uint4 bsh[2048];   // 32 KB, fragment-major: slot (nf*4+kf)*64 + lane
  const int tid = threadIdx.x;
  const int l = tid & 63;
  const int w = tid >> 6;
  const int row0 = blockIdx.x * 64 + w * 16;

  // stage Wt fragments (linear ds_write, conflict-free; W is L2-resident)
  #pragma unroll
  for (int it = 0; it < 8; ++it) {
    int s = it * 256 + tid;
    int nf = s >> 8, kf = (s >> 6) & 3, sl = s & 63;
    int col = nf * 16 + (sl & 15);
    bsh[s] = *(const uint4*)(Wtb + col * FD + kf * 32 + (sl >> 4) * 8);
  }

  // A fragments straight to registers: row = l&15, k = kf*32 + (l>>4)*8 + j
  const int arow = row0 + (l & 15);
  bf16x8 a[4];
  if (arow < n) {
    if (FUSEA) {
      const uint4* agp = (const uint4*)(Ab + (size_t)arow * FD + (l >> 4) * 8);
      const uint4* rsp = (const uint4*)(residA + (size_t)arow * FD + (l >> 4) * 8);
      uint4* xop = xout ? (uint4*)(xout + (size_t)arow * FD + (l >> 4) * 8) : nullptr;
      #pragma unroll
      for (int kf = 0; kf < 4; ++kf) {
        uint4 ag = agp[kf * 4];
        uint4 rs = rsp[kf * 4];
        int cb4 = kf * 8 + (l >> 4) * 2;   // float4 index of col base
        float4 s0 = ((const float4*)svA)[cb4];
        float4 s1 = ((const float4*)svA)[cb4 + 1];
        float4 t0 = ((const float4*)tvA)[cb4];
        float4 t1 = ((const float4*)tvA)[cb4 + 1];
        uint4 pk;
        pk.x = pack_bf2(fmaxf(fmaf(bf_lo(ag.x), s0.x, t0.x), 0.f) + bf_lo(rs.x),
                        fmaxf(fmaf(bf_hi(ag.x), s0.y, t0.y), 0.f) + bf_hi(rs.x));
        pk.y = pack_bf2(fmaxf(fmaf(bf_lo(ag.y), s0.z, t0.z), 0.f) + bf_lo(rs.y),
                        fmaxf(fmaf(bf_hi(ag.y), s0.w, t0.w), 0.f) + bf_hi(rs.y));
        pk.z = pack_bf2(fmaxf(fmaf(bf_lo(ag.z), s1.x, t1.x), 0.f) + bf_lo(rs.z),
                        fmaxf(fmaf(bf_hi(ag.z), s1.y, t1.y), 0.f) + bf_hi(rs.z));
        pk.w = pack_bf2(fmaxf(fmaf(bf_lo(ag.w), s1.z, t1.z), 0.f) + bf_lo(rs.w),
                        fmaxf(fmaf(bf_hi(ag.w), s1.w, t1.w), 0.f) + bf_hi(rs.w));
        a[kf] = *(bf16x8*)&pk;
        if (xop) xop[kf * 4] = pk;
      }
    } else {
      const uint4* ap = (const uint4*)(Ab + (size_t)arow * FD + (l >> 4) * 8);
      #pragma unroll
      for (int kf = 0; kf < 4; ++kf) { uint4 t = ap[kf * 4]; a[kf] = *(bf16x8*)&t; }
    }
  } else {
    #pragma unroll
    for (int kf = 0; kf < 4; ++kf) a[kf] = (bf16x8)(short)0;
  }

  __syncthreads();

  f32x4 acc[8];
  #pragma unroll
  for (int nf = 0; nf < 8; ++nf) acc[nf] = (f32x4)(0.0f);

  #pragma unroll
  for (int nf = 0; nf < 8; ++nf) {
    #pragma unroll
    for (int kf = 0; kf < 4; ++kf) {
      uint4 braw = bsh[(nf * 4 + kf) * 64 + l];
      acc[nf] = __builtin_amdgcn_mfma_f32_16x16x32_bf16(a[kf], *(bf16x8*)&braw, acc[nf], 0, 0, 0);
    }
  }

  // epilogue: C row = row0 + (l>>4)*4 + i, col = nf*16 + (l&15)
  if (EPI == 2) {
    float hsum[4] = {0.f, 0.f, 0.f, 0.f};
    #pragma unroll
    for (int nf = 0; nf < 8; ++nf) {
      int col = nf * 16 + (l & 15);
      float bm = bias[col];
      float hwc = hw[col];
      #pragma unroll
      for (int i = 0; i < 4; ++i)
        hsum[i] += fmaxf(acc[nf][i] + bm, 0.f) * hwc;
    }
    #pragma unroll
    for (int i = 0; i < 4; ++i) {
      #pragma unroll
      for (int off = 1; off < 16; off <<= 1) hsum[i] += __shfl_xor(hsum[i], off);
    }
    if ((l & 15) == 0) {
      float hb0 = hb[0];
      #pragma unroll
      for (int i = 0; i < 4; ++i) {
        int r = row0 + (l >> 4) * 4 + i;
        if (r < n) ((float*)Cout)[r] = hsum[i] + hb0;
      }
    }
  } else {
    unsigned short* outp = (unsigned short*)Cout;
    #pragma unroll
    for (int nf = 0; nf < 8; ++nf) {
      int col = nf * 16 + (l & 15);
      float s = (EPI == 1) ? sv[col] : 0.f;
      float t = (EPI == 1) ? tv[col] : 0.f;
      #pragma unroll
      for (int i = 0; i < 4; ++i) {
        int r = row0 + (l >> 4) * 4 + i;
        if (r < n) {
          float v = acc[nf][i];
          if (EPI == 1) {
            float ag = bf2f_us(aggb[(size_t)r * FD + col]);
            v += fmaxf(fmaf(ag, s, t), 0.f);
          }
          outp[(size_t)r * FD + col] = f2bf(v);
        }
      }
    }
  }
}

// ---------------- aggregation (bf16 rows) + fused GraphNorm stats ----------------
// 4 rows per wave (16 lanes x uint4 = 16B/lane = 8 bf16 cols), edge loop unrolled x4 + x2 tail:
// up to 16 outstanding gathers per wave to hide L2/L3 latency.
__device__ __forceinline__ void acc8(float* a, uint4 u, float wn) {
  a[0] = fmaf(wn, bf_lo(u.x), a[0]); a[1] = fmaf(wn, bf_hi(u.x), a[1]);
  a[2] = fmaf(wn, bf_lo(u.y), a[2]); a[3] = fmaf(wn, bf_hi(u.y), a[3]);
  a[4] = fmaf(wn, bf_lo(u.z), a[4]); a[5] = fmaf(wn, bf_hi(u.z), a[5]);
  a[6] = fmaf(wn, bf_lo(u.w), a[6]); a[7] = fmaf(wn, bf_hi(u.w), a[7]);
}

__global__ __launch_bounds__(256) void agg_bf16(const uint4* __restrict__ hw4, uint4* __restrict__ agg4,
    const int* __restrict__ indptr, const int* __restrict__ csr_src, const float* __restrict__ csr_norm,
    const float* __restrict__ dinv, const float* __restrict__ bias,
    float* __restrict__ colsum, float* __restrict__ colsum2, int n)
{
  __shared__ float sredS[4][4][16][8];
  __shared__ float sredQ[4][4][16][8];
  const int wv = threadIdx.x >> 6;
  const int lane = threadIdx.x & 63;
  const int q = lane >> 4;
  const int l16 = lane & 15;
  const int gs = blockIdx.x * 16 + wv * 4 + q;
  const int ns = gridDim.x * 16;
  const float4 b0 = ((const float4*)bias)[l16 * 2];
  const float4 b1 = ((const float4*)bias)[l16 * 2 + 1];
  float st[8], sq[8];
  #pragma unroll
  for (int j = 0; j < 8; ++j) { st[j] = 0.f; sq[j] = 0.f; }

  for (int c = gs; c < n; c += ns) {
    float di = dinv[c];
    float self = di * di;
    uint4 su = hw4[(size_t)c * 16 + l16];
    float a[8];
    a[0] = fmaf(self, bf_lo(su.x), b0.x); a[1] = fmaf(self, bf_hi(su.x), b0.y);
    a[2] = fmaf(self, bf_lo(su.y), b0.z); a[3] = fmaf(self, bf_hi(su.y), b0.w);
    a[4] = fmaf(self, bf_lo(su.z), b1.x); a[5] = fmaf(self, bf_hi(su.z), b1.y);
    a[6] = fmaf(self, bf_lo(su.w), b1.z); a[7] = fmaf(self, bf_hi(su.w), b1.w);
    int e = indptr[c];
    const int e1 = indptr[c + 1];
    for (; e + 4 <= e1; e += 4) {
      int s0 = csr_src[e], s1 = csr_src[e + 1], s2 = csr_src[e + 2], s3 = csr_src[e + 3];
      float w0 = csr_norm[e], w1 = csr_norm[e + 1], w2 = csr_norm[e + 2], w3 = csr_norm[e + 3];
      uint4 u0 = hw4[(size_t)s0 * 16 + l16];
      uint4 u1 = hw4[(size_t)s1 * 16 + l16];
      uint4 u2 = hw4[(size_t)s2 * 16 + l16];
      uint4 u3 = hw4[(size_t)s3 * 16 + l16];
      acc8(a, u0, w0); acc8(a, u1, w1); acc8(a, u2, w2); acc8(a, u3, w3);
    }
    if (e + 2 <= e1) {
      int s0 = csr_src[e], s1 = csr_src[e + 1];
      float w0 = csr_norm[e], w1 = csr_norm[e + 1];
      uint4 u0 = hw4[(size_t)s0 * 16 + l16];
      uint4 u1 = hw4[(size_t)s1 * 16 + l16];
      acc8(a, u0, w0); acc8(a, u1, w1);
      e += 2;
    }
    if (e < e1) {
      int s0 = csr_src[e];
      float w0 = csr_norm[e];
      uint4 u0 = hw4[(size_t)s0 * 16 + l16];
      acc8(a, u0, w0);
    }
    uint4 o;
    o.x = pack_bf2(a[0], a[1]); o.y = pack_bf2(a[2], a[3]);
    o.z = pack_bf2(a[4], a[5]); o.w = pack_bf2(a[6], a[7]);
    agg4[(size_t)c * 16 + l16] = o;
    #pragma unroll
    for (int j = 0; j < 8; ++j) { st[j] += a[j]; sq[j] += a[j] * a[j]; }
  }

  #pragma unroll
  for (int j = 0; j < 8; ++j) { sredS[wv][q][l16][j] = st[j]; sredQ[wv][q][l16][j] = sq[j]; }
  __syncthreads();
  int t = threadIdx.x;
  int which = t >> 7, cc = t & 127;
  int rl = cc >> 3, rk = cc & 7;
  float v = 0.f;
  #pragma unroll
  for (int w2 = 0; w2 < 4; ++w2)
    #pragma unroll
    for (int q2 = 0; q2 < 4; ++q2)
      v += which ? sredQ[w2][q2][rl][rk] : sredS[w2][q2][rl][rk];
  atomicAdd(which ? &colsum2[cc] : &colsum[cc], v);
}

// ---------------- GraphNorm scalars ----------------
__global__ void finalize_stats(const float* __restrict__ colsum, const float* __restrict__ colsum2,
    const float* __restrict__ gnw, const float* __restrict__ gnb, const float* __restrict__ ms,
    float* __restrict__ sv, float* __restrict__ tv, float inv_n)
{
  int d = threadIdx.x;
  if (d < FD) {
    float mean = colsum[d] * inv_n;
    float m2 = colsum2[d] * inv_n;
    float m = ms[d];
    float var = m2 - 2.f * m * mean * mean + m * m * mean * mean;
    float s = gnw[d] * rsqrtf(var + 1e-5f);
    sv[d] = s;
    tv[d] = gnb[d] - m * mean * s;
  }
}

// ---------------- launcher ----------------
extern "C" void kernel_launch(void* const* d_in, const int* in_sizes, int n_in,
                              void* d_out, int out_size, void* d_ws, size_t ws_size,
                              hipStream_t stream) {
  const float* x0      = (const float*)d_in[0];
  const int* ei        = (const int*)d_in[1];   // int32 per harness conversion
  const float* conv_w  = (const float*)d_in[2];
  const float* conv_b  = (const float*)d_in[3];
  const float* gn_w    = (const float*)d_in[4];
  const float* gn_b    = (const float*)d_in[5];
  const float* gn_ms   = (const float*)d_in[6];
  const float* proj_w  = (const float*)d_in[7];
  const float* mlp_w   = (const float*)d_in[8];
  const float* mlp_b   = (const float*)d_in[9];
  const float* head_w  = (const float*)d_in[10];
  const float* head_b  = (const float*)d_in[11];
  float* out = (float*)d_out;

  const int n = in_sizes[0] / FD;
  const int e = in_sizes[1] / 2;
  const size_t ND = (size_t)n * FD;

  unsigned short* xb0  = (unsigned short*)d_ws;  // x0, later x2
  unsigned short* xb1  = xb0 + ND;               // x1
  unsigned short* hwb  = xb1 + ND;
  unsigned short* aggb = hwb + ND;
  unsigned short* Wtb  = aggb + ND;              // 5 * 16384 bf16
  float* csr_norm = (float*)(Wtb + 5 * 16384);
  float* dinv     = csr_norm + e;
  float* stats    = dinv + n;                    // colsum[3][128] then colsum2[3][128]
  float* sv       = stats + 768;
  float* tv       = sv + FD;
  int* deg     = (int*)(tv + FD);
  int* fill    = deg + n;
  int* indptr  = fill + n;
  int* tmp     = indptr + (n + 1);
  int* partials= tmp + n;
  int* csr_src = partials + 1024;

  const int nb256_n = (n + 255) / 256;
  const int nb256_e = (e + 255) / 256;
  const int nb128_n = (n + 127) / 128;

  // ---- graph preprocessing ----
  init_kernel<<<nb256_n, 256, 0, stream>>>(deg, fill, stats, n);
  edge_count_kernel<<<nb256_e, 256, 0, stream>>>(ei, e, deg);
  scan1_kernel<<<nb128_n, 128, 0, stream>>>(deg, n, tmp, partials, dinv);
  scan2_kernel<<<1, 1024, 0, stream>>>(partials, nb128_n);
  scan3_kernel<<<nb128_n, 128, 0, stream>>>(tmp, partials, indptr, n);
  fill_kernel<<<nb256_e, 256, 0, stream>>>(ei, e, indptr, fill, dinv, csr_src, csr_norm);

  // ---- bf16 prep ----
  prep_w<<<320, 256, 0, stream>>>(conv_w, proj_w, mlp_w, Wtb);
  convert_x0<<<2048, 256, 0, stream>>>(x0, (unsigned int*)xb0, (int)(ND / 2));

  const int gemm_grid = (n + 63) / 64;
  const float inv_n = 1.f / (float)n;
  const unsigned short* Wt_conv0 = Wtb;
  const unsigned short* Wt_conv1 = Wtb + 16384;
  const unsigned short* Wt_conv2 = Wtb + 2 * 16384;
  const unsigned short* Wt_proj  = Wtb + 3 * 16384;
  const unsigned short* Wt_mlp   = Wtb + 4 * 16384;

  // ---- layer 0 ----
  mfma_gemm<0, false><<<gemm_grid, 256, 0, stream>>>(xb0, Wt_conv0, hwb, n,
      nullptr, nullptr, nullptr, nullptr, nullptr, nullptr, nullptr, nullptr, nullptr, nullptr);
  agg_bf16<<<2048, 256, 0, stream>>>((const uint4*)hwb, (uint4*)aggb, indptr, csr_src, csr_norm, dinv,
                                     conv_b + 0 * FD, stats + 0 * FD, stats + 384 + 0 * FD, n);
  finalize_stats<<<1, 128, 0, stream>>>(stats + 0 * FD, stats + 384 + 0 * FD,
      gn_w + 0 * FD, gn_b + 0 * FD, gn_ms + 0 * FD, sv, tv, inv_n);
  // x1 = relu(norm(agg0)) + x0 @ proj   (epilogue-side fusion)
  mfma_gemm<1, false><<<gemm_grid, 256, 0, stream>>>(xb0, Wt_proj, xb1, n,
      aggb, sv, tv, nullptr, nullptr, nullptr, nullptr, nullptr, nullptr, nullptr);

  // ---- layer 1 ----
  mfma_gemm<0, false><<<gemm_grid, 256, 0, stream>>>(xb1, Wt_conv1, hwb, n,
      nullptr, nullptr, nullptr, nullptr, nullptr, nullptr, nullptr, nullptr, nullptr, nullptr);
  agg_bf16<<<2048, 256, 0, stream>>>((const uint4*)hwb, (uint4*)aggb, indptr, csr_src, csr_norm, dinv,
                                     conv_b + 1 * FD, stats + 1 * FD, stats + 384 + 1 * FD, n);
  finalize_stats<<<1, 128, 0, stream>>>(stats + 1 * FD, stats + 384 + 1 * FD,
      gn_w + 1 * FD, gn_b + 1 * FD, gn_ms + 1 * FD, sv, tv, inv_n);

  // ---- layer 2: conv GEMM with A = x2 = relu(agg1*s1+t1)+x1 computed inline; writes x2 -> xb0 ----
  mfma_gemm<0, true><<<gemm_grid, 256, 0, stream>>>(aggb, Wt_conv2, hwb, n,
      nullptr, nullptr, nullptr, nullptr, nullptr, nullptr, sv, tv, xb1, xb0);
  agg_bf16<<<2048, 256, 0, stream>>>((const uint4*)hwb, (uint4*)aggb, indptr, csr_src, csr_norm, dinv,
                                     conv_b + 2 * FD, stats + 2 * FD, stats + 384 + 2 * FD, n);
  finalize_stats<<<1, 128, 0, stream>>>(stats + 2 * FD, stats + 384 + 2 * FD,
      gn_w + 2 * FD, gn_b + 2 * FD, gn_ms + 2 * FD, sv, tv, inv_n);

  // ---- MLP + head: A = x3 = relu(agg2*s2+t2)+x2 inline (not materialized), f32 out ----
  mfma_gemm<2, true><<<gemm_grid, 256, 0, stream>>>(aggb, Wt_mlp, out, n,
      nullptr, nullptr, nullptr, mlp_b, head_w, head_b, sv, tv, xb0, nullptr);
}

// Round 8
// 410.371 us; speedup vs baseline: 1.8476x; 1.0226x over previous
//
#include <hip/hip_runtime.h>

#define FD 128

typedef __attribute__((ext_vector_type(8))) short bf16x8;
typedef __attribute__((ext_vector_type(4))) float f32x4;

__device__ __forceinline__ unsigned short f2bf(float f) {
  unsigned int u = __float_as_uint(f);
  unsigned int r = (u + 0x7fffu + ((u >> 16) & 1u)) >> 16;
  return (unsigned short)r;
}
__device__ __forceinline__ float bf_lo(unsigned int u) { return __uint_as_float(u << 16); }
__device__ __forceinline__ float bf_hi(unsigned int u) { return __uint_as_float(u & 0xffff0000u); }
__device__ __forceinline__ unsigned int pack_bf2(float a, float b) {
  return (unsigned int)f2bf(a) | ((unsigned int)f2bf(b) << 16);
}
__device__ __forceinline__ float bf2f_us(unsigned short s) { return __uint_as_float(((unsigned int)s) << 16); }

// ---------------- graph preprocessing ----------------
__global__ __launch_bounds__(256) void init_kernel(int* __restrict__ deg, int* __restrict__ fill,
    float* __restrict__ stats, int n) {
  int i = blockIdx.x * 256 + threadIdx.x;
  if (i < n) { deg[i] = 1; fill[i] = 0; }
  if (i < 768) stats[i] = 0.f;   // colsum[3][128] + colsum2[3][128]
}

__global__ __launch_bounds__(256) void edge_count_kernel(const int* __restrict__ ei, int e, int* __restrict__ deg) {
  int i = blockIdx.x * 256 + threadIdx.x;
  if (i < e) atomicAdd(&deg[ei[e + i]], 1);
}

// scan over (deg-1) to get CSR edge offsets; also emits dinv = rsqrt(deg)
__global__ __launch_bounds__(128) void scan1_kernel(const int* __restrict__ deg, int n,
    int* __restrict__ tmp, int* __restrict__ partials, float* __restrict__ dinv) {
  __shared__ int s[128];
  int b = blockIdx.x, t = threadIdx.x;
  int i = b * 128 + t;
  int d = (i < n) ? deg[i] : 1;
  if (i < n) dinv[i] = rsqrtf((float)d);
  s[t] = (i < n) ? (d - 1) : 0;
  __syncthreads();
  for (int off = 1; off < 128; off <<= 1) {
    int u = (t >= off) ? s[t - off] : 0;
    __syncthreads();
    s[t] += u;
    __syncthreads();
  }
  if (i < n) tmp[i] = s[t];
  if (t == 127) partials[b] = s[127];
}

__global__ __launch_bounds__(1024) void scan2_kernel(int* __restrict__ partials, int nb) {
  __shared__ int s[1024];
  int t = threadIdx.x;
  s[t] = (t < nb) ? partials[t] : 0;
  __syncthreads();
  for (int off = 1; off < 1024; off <<= 1) {
    int u = (t >= off) ? s[t - off] : 0;
    __syncthreads();
    s[t] += u;
    __syncthreads();
  }
  if (t < nb) partials[t] = (t == 0) ? 0 : s[t - 1];
}

__global__ __launch_bounds__(128) void scan3_kernel(const int* __restrict__ tmp, const int* __restrict__ partials, int* __restrict__ indptr, int n) {
  int i = blockIdx.x * 128 + threadIdx.x;
  if (i < n) indptr[i + 1] = tmp[i] + partials[blockIdx.x];
  if (i == 0) indptr[0] = 0;
}

__global__ __launch_bounds__(256) void fill_kernel(const int* __restrict__ ei, int e,
    const int* __restrict__ indptr, int* __restrict__ fill, const float* __restrict__ dinv,
    int* __restrict__ csr_src, float* __restrict__ csr_norm) {
  int i = blockIdx.x * 256 + threadIdx.x;
  if (i < e) {
    int r = ei[i];
    int c = ei[e + i];
    int pos = indptr[c] + atomicAdd(&fill[c], 1);
    csr_src[pos] = r;
    csr_norm[pos] = dinv[r] * dinv[c];
  }
}

// ---------------- weight prep: Wt[m][col][k] = W[m][k][col] as bf16 ----------------
__global__ __launch_bounds__(256) void prep_w(const float* __restrict__ conv_w, const float* __restrict__ proj_w,
    const float* __restrict__ mlp_w, unsigned short* __restrict__ Wtb) {
  int idx = blockIdx.x * 256 + threadIdx.x;   // 5*16384 total
  int m = idx >> 14;
  int o = idx & 16383;
  int col = o >> 7, k = o & 127;
  const float* src = (m < 3) ? (conv_w + m * 16384) : ((m == 3) ? proj_w : mlp_w);
  Wtb[idx] = f2bf(src[k * FD + col]);
}

// ---------------- x0 f32 -> bf16 ----------------
__global__ __launch_bounds__(256) void convert_x0(const float* __restrict__ x, unsigned int* __restrict__ xb, int total2) {
  int i = blockIdx.x * blockDim.x + threadIdx.x;
  int stride = gridDim.x * blockDim.x;
  for (; i < total2; i += stride) {
    float2 v = ((const float2*)x)[i];
    xb[i] = pack_bf2(v.x, v.y);
  }
}

// ---------------- MFMA GEMM: C[n,128] = A[n,128]bf16 @ W[128,128] ----------------
// EPI 0: store bf16 A@W
// EPI 1: store bf16 relu(agg*s+t) + A@W        (layer-0 apply fused with proj GEMM, epilogue side)
// EPI 2: out[r] = relu(A@W + bias) . head_w + head_b   (MLP+head fused, f32 out)
// FUSEA: A := relu(Ab*svA+tvA) + residA computed inline in the A-fragment loader;
//        if xout != nullptr the computed A rows are also written back (materializes x2).
template<int EPI, bool FUSEA>
__global__ __launch_bounds__(256) void mfma_gemm(const unsigned short* __restrict__ Ab,
    const unsigned short* __restrict__ Wtb, void* __restrict__ Cout, int n,
    const unsigned short* __restrict__ aggb, const float* __restrict__ sv, const float* __restrict__ tv,
    const float* __restrict__ bias, const float* __restrict__ hw, const float* __restrict__ hb,
    const float* __restrict__ svA, const float* __restrict__ tvA,
    const unsigned short* __restrict__ residA, unsigned short* __restrict__ xout)
{
  __shared__ uint4 bsh[2048];   // 32 KB, fragment-major: slot (nf*4+kf)*64 + lane
  const int tid = threadIdx.x;
  const int l = tid & 63;
  const int w = tid >> 6;
  const int row0 = blockIdx.x * 64 + w * 16;

  // stage Wt fragments (linear ds_write, conflict-free; W is L2-resident)
  #pragma unroll
  for (int it = 0; it < 8; ++it) {
    int s = it * 256 + tid;
    int nf = s >> 8, kf = (s >> 6) & 3, sl = s & 63;
    int col = nf * 16 + (sl & 15);
    bsh[s] = *(const uint4*)(Wtb + col * FD + kf * 32 + (sl >> 4) * 8);
  }

  // A fragments straight to registers: row = l&15, k = kf*32 + (l>>4)*8 + j
  const int arow = row0 + (l & 15);
  bf16x8 a[4];
  if (arow < n) {
    if (FUSEA) {
      const uint4* agp = (const uint4*)(Ab + (size_t)arow * FD + (l >> 4) * 8);
      const uint4* rsp = (const uint4*)(residA + (size_t)arow * FD + (l >> 4) * 8);
      uint4* xop = xout ? (uint4*)(xout + (size_t)arow * FD + (l >> 4) * 8) : nullptr;
      #pragma unroll
      for (int kf = 0; kf < 4; ++kf) {
        uint4 ag = agp[kf * 4];
        uint4 rs = rsp[kf * 4];
        int cb4 = kf * 8 + (l >> 4) * 2;   // float4 index of col base
        float4 s0 = ((const float4*)svA)[cb4];
        float4 s1 = ((const float4*)svA)[cb4 + 1];
        float4 t0 = ((const float4*)tvA)[cb4];
        float4 t1 = ((const float4*)tvA)[cb4 + 1];
        uint4 pk;
        pk.x = pack_bf2(fmaxf(fmaf(bf_lo(ag.x), s0.x, t0.x), 0.f) + bf_lo(rs.x),
                        fmaxf(fmaf(bf_hi(ag.x), s0.y, t0.y), 0.f) + bf_hi(rs.x));
        pk.y = pack_bf2(fmaxf(fmaf(bf_lo(ag.y), s0.z, t0.z), 0.f) + bf_lo(rs.y),
                        fmaxf(fmaf(bf_hi(ag.y), s0.w, t0.w), 0.f) + bf_hi(rs.y));
        pk.z = pack_bf2(fmaxf(fmaf(bf_lo(ag.z), s1.x, t1.x), 0.f) + bf_lo(rs.z),
                        fmaxf(fmaf(bf_hi(ag.z), s1.y, t1.y), 0.f) + bf_hi(rs.z));
        pk.w = pack_bf2(fmaxf(fmaf(bf_lo(ag.w), s1.z, t1.z), 0.f) + bf_lo(rs.w),
                        fmaxf(fmaf(bf_hi(ag.w), s1.w, t1.w), 0.f) + bf_hi(rs.w));
        a[kf] = *(bf16x8*)&pk;
        if (xop) xop[kf * 4] = pk;
      }
    } else {
      const uint4* ap = (const uint4*)(Ab + (size_t)arow * FD + (l >> 4) * 8);
      #pragma unroll
      for (int kf = 0; kf < 4; ++kf) { uint4 t = ap[kf * 4]; a[kf] = *(bf16x8*)&t; }
    }
  } else {
    #pragma unroll
    for (int kf = 0; kf < 4; ++kf) a[kf] = (bf16x8)(short)0;
  }

  __syncthreads();

  f32x4 acc[8];
  #pragma unroll
  for (int nf = 0; nf < 8; ++nf) acc[nf] = (f32x4)(0.0f);

  #pragma unroll
  for (int nf = 0; nf < 8; ++nf) {
    #pragma unroll
    for (int kf = 0; kf < 4; ++kf) {
      uint4 braw = bsh[(nf * 4 + kf) * 64 + l];
      acc[nf] = __builtin_amdgcn_mfma_f32_16x16x32_bf16(a[kf], *(bf16x8*)&braw, acc[nf], 0, 0, 0);
    }
  }

  // epilogue: C row = row0 + (l>>4)*4 + i, col = nf*16 + (l&15)
  if (EPI == 2) {
    float hsum[4] = {0.f, 0.f, 0.f, 0.f};
    #pragma unroll
    for (int nf = 0; nf < 8; ++nf) {
      int col = nf * 16 + (l & 15);
      float bm = bias[col];
      float hwc = hw[col];
      #pragma unroll
      for (int i = 0; i < 4; ++i)
        hsum[i] += fmaxf(acc[nf][i] + bm, 0.f) * hwc;
    }
    #pragma unroll
    for (int i = 0; i < 4; ++i) {
      #pragma unroll
      for (int off = 1; off < 16; off <<= 1) hsum[i] += __shfl_xor(hsum[i], off);
    }
    if ((l & 15) == 0) {
      float hb0 = hb[0];
      #pragma unroll
      for (int i = 0; i < 4; ++i) {
        int r = row0 + (l >> 4) * 4 + i;
        if (r < n) ((float*)Cout)[r] = hsum[i] + hb0;
      }
    }
  } else {
    unsigned short* outp = (unsigned short*)Cout;
    #pragma unroll
    for (int nf = 0; nf < 8; ++nf) {
      int col = nf * 16 + (l & 15);
      float s = (EPI == 1) ? sv[col] : 0.f;
      float t = (EPI == 1) ? tv[col] : 0.f;
      #pragma unroll
      for (int i = 0; i < 4; ++i) {
        int r = row0 + (l >> 4) * 4 + i;
        if (r < n) {
          float v = acc[nf][i];
          if (EPI == 1) {
            float ag = bf2f_us(aggb[(size_t)r * FD + col]);
            v += fmaxf(fmaf(ag, s, t), 0.f);
          }
          outp[(size_t)r * FD + col] = f2bf(v);
        }
      }
    }
  }
}

// ---------------- aggregation (bf16 rows) + fused GraphNorm stats ----------------
// 4 rows per wave (16 lanes x uint4 = full 256B row per quarter-wave), edge loop unrolled x4,
// row-level software pipeline: next row's dinv/indptr/self-row loads issued before the
// current row's edge loop so their latency hides under the edge gathers.
__device__ __forceinline__ void acc8(float* a, uint4 u, float wn) {
  a[0] = fmaf(wn, bf_lo(u.x), a[0]); a[1] = fmaf(wn, bf_hi(u.x), a[1]);
  a[2] = fmaf(wn, bf_lo(u.y), a[2]); a[3] = fmaf(wn, bf_hi(u.y), a[3]);
  a[4] = fmaf(wn, bf_lo(u.z), a[4]); a[5] = fmaf(wn, bf_hi(u.z), a[5]);
  a[6] = fmaf(wn, bf_lo(u.w), a[6]); a[7] = fmaf(wn, bf_hi(u.w), a[7]);
}

__global__ __launch_bounds__(256) void agg_bf16(const uint4* __restrict__ hw4, uint4* __restrict__ agg4,
    const int* __restrict__ indptr, const int* __restrict__ csr_src, const float* __restrict__ csr_norm,
    const float* __restrict__ dinv, const float* __restrict__ bias,
    float* __restrict__ colsum, float* __restrict__ colsum2, int n)
{
  __shared__ float sredS[4][16][9];   // stride 9: conflict-free
  __shared__ float sredQ[4][16][9];
  const int wv = threadIdx.x >> 6;
  const int lane = threadIdx.x & 63;
  const int q = lane >> 4;
  const int l16 = lane & 15;
  const int gs = blockIdx.x * 16 + wv * 4 + q;
  const int ns = gridDim.x * 16;
  const float4 b0 = ((const float4*)bias)[l16 * 2];
  const float4 b1 = ((const float4*)bias)[l16 * 2 + 1];
  float st[8], sq[8];
  #pragma unroll
  for (int j = 0; j < 8; ++j) { st[j] = 0.f; sq[j] = 0.f; }

  int c = gs;
  float di = 0.f; int e0 = 0, e1 = 0;
  uint4 su = make_uint4(0, 0, 0, 0);
  if (c < n) {
    di = dinv[c];
    e0 = indptr[c]; e1 = indptr[c + 1];
    su = hw4[(size_t)c * 16 + l16];
  }
  while (c < n) {
    // prefetch next row's header while current row's edges are processed
    const int cn = c + ns;
    float di_n = 0.f; int e0_n = 0, e1_n = 0;
    uint4 su_n = make_uint4(0, 0, 0, 0);
    if (cn < n) {
      di_n = dinv[cn];
      e0_n = indptr[cn]; e1_n = indptr[cn + 1];
      su_n = hw4[(size_t)cn * 16 + l16];
    }

    float self = di * di;
    float a[8];
    a[0] = fmaf(self, bf_lo(su.x), b0.x); a[1] = fmaf(self, bf_hi(su.x), b0.y);
    a[2] = fmaf(self, bf_lo(su.y), b0.z); a[3] = fmaf(self, bf_hi(su.y), b0.w);
    a[4] = fmaf(self, bf_lo(su.z), b1.x); a[5] = fmaf(self, bf_hi(su.z), b1.y);
    a[6] = fmaf(self, bf_lo(su.w), b1.z); a[7] = fmaf(self, bf_hi(su.w), b1.w);
    int e = e0;
    for (; e + 4 <= e1; e += 4) {
      int s0 = csr_src[e], s1 = csr_src[e + 1], s2 = csr_src[e + 2], s3 = csr_src[e + 3];
      float w0 = csr_norm[e], w1 = csr_norm[e + 1], w2 = csr_norm[e + 2], w3 = csr_norm[e + 3];
      uint4 u0 = hw4[(size_t)s0 * 16 + l16];
      uint4 u1 = hw4[(size_t)s1 * 16 + l16];
      uint4 u2 = hw4[(size_t)s2 * 16 + l16];
      uint4 u3 = hw4[(size_t)s3 * 16 + l16];
      acc8(a, u0, w0); acc8(a, u1, w1); acc8(a, u2, w2); acc8(a, u3, w3);
    }
    if (e + 2 <= e1) {
      int s0 = csr_src[e], s1 = csr_src[e + 1];
      float w0 = csr_norm[e], w1 = csr_norm[e + 1];
      uint4 u0 = hw4[(size_t)s0 * 16 + l16];
      uint4 u1 = hw4[(size_t)s1 * 16 + l16];
      acc8(a, u0, w0); acc8(a, u1, w1);
      e += 2;
    }
    if (e < e1) {
      int s0 = csr_src[e];
      float w0 = csr_norm[e];
      uint4 u0 = hw4[(size_t)s0 * 16 + l16];
      acc8(a, u0, w0);
    }
    uint4 o;
    o.x = pack_bf2(a[0], a[1]); o.y = pack_bf2(a[2], a[3]);
    o.z = pack_bf2(a[4], a[5]); o.w = pack_bf2(a[6], a[7]);
    agg4[(size_t)c * 16 + l16] = o;
    #pragma unroll
    for (int j = 0; j < 8; ++j) { st[j] += a[j]; sq[j] += a[j] * a[j]; }

    c = cn; di = di_n; e0 = e0_n; e1 = e1_n; su = su_n;
  }

  // cross-quarter reduce: lanes {q*16+l16} all cover col = l16*8+j
  #pragma unroll
  for (int j = 0; j < 8; ++j) {
    st[j] += __shfl_xor(st[j], 16); st[j] += __shfl_xor(st[j], 32);
    sq[j] += __shfl_xor(sq[j], 16); sq[j] += __shfl_xor(sq[j], 32);
  }
  if (q == 0) {
    #pragma unroll
    for (int j = 0; j < 8; ++j) { sredS[wv][l16][j] = st[j]; sredQ[wv][l16][j] = sq[j]; }
  }
  __syncthreads();
  int t = threadIdx.x;
  int which = t >> 7, cc = t & 127;
  int rl = cc >> 3, rk = cc & 7;
  float v = 0.f;
  #pragma unroll
  for (int w2 = 0; w2 < 4; ++w2)
    v += which ? sredQ[w2][rl][rk] : sredS[w2][rl][rk];
  atomicAdd(which ? &colsum2[cc] : &colsum[cc], v);
}

// ---------------- GraphNorm scalars ----------------
__global__ void finalize_stats(const float* __restrict__ colsum, const float* __restrict__ colsum2,
    const float* __restrict__ gnw, const float* __restrict__ gnb, const float* __restrict__ ms,
    float* __restrict__ sv, float* __restrict__ tv, float inv_n)
{
  int d = threadIdx.x;
  if (d < FD) {
    float mean = colsum[d] * inv_n;
    float m2 = colsum2[d] * inv_n;
    float m = ms[d];
    float var = m2 - 2.f * m * mean * mean + m * m * mean * mean;
    float s = gnw[d] * rsqrtf(var + 1e-5f);
    sv[d] = s;
    tv[d] = gnb[d] - m * mean * s;
  }
}

// ---------------- launcher ----------------
extern "C" void kernel_launch(void* const* d_in, const int* in_sizes, int n_in,
                              void* d_out, int out_size, void* d_ws, size_t ws_size,
                              hipStream_t stream) {
  const float* x0      = (const float*)d_in[0];
  const int* ei        = (const int*)d_in[1];   // int32 per harness conversion
  const float* conv_w  = (const float*)d_in[2];
  const float* conv_b  = (const float*)d_in[3];
  const float* gn_w    = (const float*)d_in[4];
  const float* gn_b    = (const float*)d_in[5];
  const float* gn_ms   = (const float*)d_in[6];
  const float* proj_w  = (const float*)d_in[7];
  const float* mlp_w   = (const float*)d_in[8];
  const float* mlp_b   = (const float*)d_in[9];
  const float* head_w  = (const float*)d_in[10];
  const float* head_b  = (const float*)d_in[11];
  float* out = (float*)d_out;

  const int n = in_sizes[0] / FD;
  const int e = in_sizes[1] / 2;
  const size_t ND = (size_t)n * FD;

  unsigned short* xb0  = (unsigned short*)d_ws;  // x0, later x2
  unsigned short* xb1  = xb0 + ND;               // x1
  unsigned short* hwb  = xb1 + ND;
  unsigned short* aggb = hwb + ND;
  unsigned short* Wtb  = aggb + ND;              // 5 * 16384 bf16
  float* csr_norm = (float*)(Wtb + 5 * 16384);
  float* dinv     = csr_norm + e;
  float* stats    = dinv + n;                    // colsum[3][128] then colsum2[3][128]
  float* sv       = stats + 768;
  float* tv       = sv + FD;
  int* deg     = (int*)(tv + FD);
  int* fill    = deg + n;
  int* indptr  = fill + n;
  int* tmp     = indptr + (n + 1);
  int* partials= tmp + n;
  int* csr_src = partials + 1024;

  const int nb256_n = (n + 255) / 256;
  const int nb256_e = (e + 255) / 256;
  const int nb128_n = (n + 127) / 128;

  // ---- graph preprocessing ----
  init_kernel<<<nb256_n, 256, 0, stream>>>(deg, fill, stats, n);
  edge_count_kernel<<<nb256_e, 256, 0, stream>>>(ei, e, deg);
  scan1_kernel<<<nb128_n, 128, 0, stream>>>(deg, n, tmp, partials, dinv);
  scan2_kernel<<<1, 1024, 0, stream>>>(partials, nb128_n);
  scan3_kernel<<<nb128_n, 128, 0, stream>>>(tmp, partials, indptr, n);
  fill_kernel<<<nb256_e, 256, 0, stream>>>(ei, e, indptr, fill, dinv, csr_src, csr_norm);

  // ---- bf16 prep ----
  prep_w<<<320, 256, 0, stream>>>(conv_w, proj_w, mlp_w, Wtb);
  convert_x0<<<2048, 256, 0, stream>>>(x0, (unsigned int*)xb0, (int)(ND / 2));

  const int gemm_grid = (n + 63) / 64;
  const float inv_n = 1.f / (float)n;
  const unsigned short* Wt_conv0 = Wtb;
  const unsigned short* Wt_conv1 = Wtb + 16384;
  const unsigned short* Wt_conv2 = Wtb + 2 * 16384;
  const unsigned short* Wt_proj  = Wtb + 3 * 16384;
  const unsigned short* Wt_mlp   = Wtb + 4 * 16384;

  // ---- layer 0 ----
  mfma_gemm<0, false><<<gemm_grid, 256, 0, stream>>>(xb0, Wt_conv0, hwb, n,
      nullptr, nullptr, nullptr, nullptr, nullptr, nullptr, nullptr, nullptr, nullptr, nullptr);
  agg_bf16<<<2048, 256, 0, stream>>>((const uint4*)hwb, (uint4*)aggb, indptr, csr_src, csr_norm, dinv,
                                     conv_b + 0 * FD, stats + 0 * FD, stats + 384 + 0 * FD, n);
  finalize_stats<<<1, 128, 0, stream>>>(stats + 0 * FD, stats + 384 + 0 * FD,
      gn_w + 0 * FD, gn_b + 0 * FD, gn_ms + 0 * FD, sv, tv, inv_n);
  // x1 = relu(norm(agg0)) + x0 @ proj   (epilogue-side fusion)
  mfma_gemm<1, false><<<gemm_grid, 256, 0, stream>>>(xb0, Wt_proj, xb1, n,
      aggb, sv, tv, nullptr, nullptr, nullptr, nullptr, nullptr, nullptr, nullptr);

  // ---- layer 1 ----
  mfma_gemm<0, false><<<gemm_grid, 256, 0, stream>>>(xb1, Wt_conv1, hwb, n,
      nullptr, nullptr, nullptr, nullptr, nullptr, nullptr, nullptr, nullptr, nullptr, nullptr);
  agg_bf16<<<2048, 256, 0, stream>>>((const uint4*)hwb, (uint4*)aggb, indptr, csr_src, csr_norm, dinv,
                                     conv_b + 1 * FD, stats + 1 * FD, stats + 384 + 1 * FD, n);
  finalize_stats<<<1, 128, 0, stream>>>(stats + 1 * FD, stats + 384 + 1 * FD,
      gn_w + 1 * FD, gn_b + 1 * FD, gn_ms + 1 * FD, sv, tv, inv_n);

  // ---- layer 2: conv GEMM with A = x2 = relu(agg1*s1+t1)+x1 computed inline; writes x2 -> xb0 ----
  mfma_gemm<0, true><<<gemm_grid, 256, 0, stream>>>(aggb, Wt_conv2, hwb, n,
      nullptr, nullptr, nullptr, nullptr, nullptr, nullptr, sv, tv, xb1, xb0);
  agg_bf16<<<2048, 256, 0, stream>>>((const uint4*)hwb, (uint4*)aggb, indptr, csr_src, csr_norm, dinv,
                                     conv_b + 2 * FD, stats + 2 * FD, stats + 384 + 2 * FD, n);
  finalize_stats<<<1, 128, 0, stream>>>(stats + 2 * FD, stats + 384 + 2 * FD,
      gn_w + 2 * FD, gn_b + 2 * FD, gn_ms + 2 * FD, sv, tv, inv_n);

  // ---- MLP + head: A = x3 = relu(agg2*s2+t2)+x2 inline (not materialized), f32 out ----
  mfma_gemm<2, true><<<gemm_grid, 256, 0, stream>>>(aggb, Wt_mlp, out, n,
      nullptr, nullptr, nullptr, mlp_b, head_w, head_b, sv, tv, xb0, nullptr);
}

// Round 9
// 400.970 us; speedup vs baseline: 1.8909x; 1.0234x over previous
//
#include <hip/hip_runtime.h>

#define FD 128

typedef __attribute__((ext_vector_type(8))) short bf16x8;
typedef __attribute__((ext_vector_type(4))) float f32x4;

__device__ __forceinline__ unsigned short f2bf(float f) {
  unsigned int u = __float_as_uint(f);
  unsigned int r = (u + 0x7fffu + ((u >> 16) & 1u)) >> 16;
  return (unsigned short)r;
}
__device__ __forceinline__ float bf_lo(unsigned int u) { return __uint_as_float(u << 16); }
__device__ __forceinline__ float bf_hi(unsigned int u) { return __uint_as_float(u & 0xffff0000u); }
__device__ __forceinline__ unsigned int pack_bf2(float a, float b) {
  return (unsigned int)f2bf(a) | ((unsigned int)f2bf(b) << 16);
}

// ---------------- graph preprocessing ----------------
__global__ __launch_bounds__(256) void init_kernel(int* __restrict__ deg, int* __restrict__ fill,
    float* __restrict__ stats, int n) {
  int i = blockIdx.x * 256 + threadIdx.x;
  if (i < n) { deg[i] = 1; fill[i] = 0; }
  if (i < 768) stats[i] = 0.f;   // colsum[3][128] + colsum2[3][128]
}

__global__ __launch_bounds__(256) void edge_count_kernel(const int* __restrict__ ei, int e, int* __restrict__ deg) {
  int i = blockIdx.x * 256 + threadIdx.x;
  if (i < e) atomicAdd(&deg[ei[e + i]], 1);
}

// scan over (deg-1) to get CSR edge offsets; also emits dinv = rsqrt(deg)
__global__ __launch_bounds__(128) void scan1_kernel(const int* __restrict__ deg, int n,
    int* __restrict__ tmp, int* __restrict__ partials, float* __restrict__ dinv) {
  __shared__ int s[128];
  int b = blockIdx.x, t = threadIdx.x;
  int i = b * 128 + t;
  int d = (i < n) ? deg[i] : 1;
  if (i < n) dinv[i] = rsqrtf((float)d);
  s[t] = (i < n) ? (d - 1) : 0;
  __syncthreads();
  for (int off = 1; off < 128; off <<= 1) {
    int u = (t >= off) ? s[t - off] : 0;
    __syncthreads();
    s[t] += u;
    __syncthreads();
  }
  if (i < n) tmp[i] = s[t];
  if (t == 127) partials[b] = s[127];
}

__global__ __launch_bounds__(1024) void scan2_kernel(int* __restrict__ partials, int nb) {
  __shared__ int s[1024];
  int t = threadIdx.x;
  s[t] = (t < nb) ? partials[t] : 0;
  __syncthreads();
  for (int off = 1; off < 1024; off <<= 1) {
    int u = (t >= off) ? s[t - off] : 0;
    __syncthreads();
    s[t] += u;
    __syncthreads();
  }
  if (t < nb) partials[t] = (t == 0) ? 0 : s[t - 1];
}

__global__ __launch_bounds__(128) void scan3_kernel(const int* __restrict__ tmp, const int* __restrict__ partials, int* __restrict__ indptr, int n) {
  int i = blockIdx.x * 128 + threadIdx.x;
  if (i < n) indptr[i + 1] = tmp[i] + partials[blockIdx.x];
  if (i == 0) indptr[0] = 0;
}

__global__ __launch_bounds__(256) void fill_kernel(const int* __restrict__ ei, int e,
    const int* __restrict__ indptr, int* __restrict__ fill, const float* __restrict__ dinv,
    int* __restrict__ csr_src, float* __restrict__ csr_norm) {
  int i = blockIdx.x * 256 + threadIdx.x;
  if (i < e) {
    int r = ei[i];
    int c = ei[e + i];
    int pos = indptr[c] + atomicAdd(&fill[c], 1);
    csr_src[pos] = r;
    csr_norm[pos] = dinv[r] * dinv[c];
  }
}

// ---------------- weight prep: Wt[m][col][k] = W[m][k][col] as bf16 ----------------
__global__ __launch_bounds__(256) void prep_w(const float* __restrict__ conv_w, const float* __restrict__ proj_w,
    const float* __restrict__ mlp_w, unsigned short* __restrict__ Wtb) {
  int idx = blockIdx.x * 256 + threadIdx.x;   // 5*16384 total
  int m = idx >> 14;
  int o = idx & 16383;
  int col = o >> 7, k = o & 127;
  const float* src = (m < 3) ? (conv_w + m * 16384) : ((m == 3) ? proj_w : mlp_w);
  Wtb[idx] = f2bf(src[k * FD + col]);
}

// ---------------- layer-0 dual GEMM: hw0 = x0@W0, xp = x0@P (A loaded once from f32) ----------------
__global__ __launch_bounds__(256) void gemm_dual(const float* __restrict__ x0,
    const unsigned short* __restrict__ W0t, const unsigned short* __restrict__ Pt,
    unsigned short* __restrict__ hw0, unsigned short* __restrict__ xp, int n)
{
  __shared__ uint4 bsh[2048];   // 32 KB, fragment-major: slot (nf*4+kf)*64 + lane
  const int tid = threadIdx.x;
  const int l = tid & 63;
  const int w = tid >> 6;
  const int row0 = blockIdx.x * 64 + w * 16;

  // stage W0 fragments
  #pragma unroll
  for (int it = 0; it < 8; ++it) {
    int s = it * 256 + tid;
    int nf = s >> 8, kf = (s >> 6) & 3, sl = s & 63;
    int col = nf * 16 + (sl & 15);
    bsh[s] = *(const uint4*)(W0t + col * FD + kf * 32 + (sl >> 4) * 8);
  }

  // A fragments from f32, converted inline: row = l&15, k = kf*32 + (l>>4)*8 + j
  const int arow = row0 + (l & 15);
  bf16x8 a[4];
  if (arow < n) {
    const float4* ap = (const float4*)(x0 + (size_t)arow * FD + (l >> 4) * 8);
    #pragma unroll
    for (int kf = 0; kf < 4; ++kf) {
      float4 f0 = ap[kf * 8];
      float4 f1 = ap[kf * 8 + 1];
      uint4 pk;
      pk.x = pack_bf2(f0.x, f0.y); pk.y = pack_bf2(f0.z, f0.w);
      pk.z = pack_bf2(f1.x, f1.y); pk.w = pack_bf2(f1.z, f1.w);
      a[kf] = *(bf16x8*)&pk;
    }
  } else {
    #pragma unroll
    for (int kf = 0; kf < 4; ++kf) a[kf] = (bf16x8)(short)0;
  }

  __syncthreads();

  f32x4 acc[8];
  #pragma unroll
  for (int nf = 0; nf < 8; ++nf) acc[nf] = (f32x4)(0.0f);
  #pragma unroll
  for (int nf = 0; nf < 8; ++nf)
    #pragma unroll
    for (int kf = 0; kf < 4; ++kf) {
      uint4 braw = bsh[(nf * 4 + kf) * 64 + l];
      acc[nf] = __builtin_amdgcn_mfma_f32_16x16x32_bf16(a[kf], *(bf16x8*)&braw, acc[nf], 0, 0, 0);
    }

  __syncthreads();   // everyone done reading W0 from LDS

  // stage P fragments + store hw0
  #pragma unroll
  for (int it = 0; it < 8; ++it) {
    int s = it * 256 + tid;
    int nf = s >> 8, kf = (s >> 6) & 3, sl = s & 63;
    int col = nf * 16 + (sl & 15);
    bsh[s] = *(const uint4*)(Pt + col * FD + kf * 32 + (sl >> 4) * 8);
  }
  #pragma unroll
  for (int nf = 0; nf < 8; ++nf) {
    int col = nf * 16 + (l & 15);
    #pragma unroll
    for (int i = 0; i < 4; ++i) {
      int r = row0 + (l >> 4) * 4 + i;
      if (r < n) hw0[(size_t)r * FD + col] = f2bf(acc[nf][i]);
    }
  }

  __syncthreads();

  #pragma unroll
  for (int nf = 0; nf < 8; ++nf) acc[nf] = (f32x4)(0.0f);
  #pragma unroll
  for (int nf = 0; nf < 8; ++nf)
    #pragma unroll
    for (int kf = 0; kf < 4; ++kf) {
      uint4 braw = bsh[(nf * 4 + kf) * 64 + l];
      acc[nf] = __builtin_amdgcn_mfma_f32_16x16x32_bf16(a[kf], *(bf16x8*)&braw, acc[nf], 0, 0, 0);
    }
  #pragma unroll
  for (int nf = 0; nf < 8; ++nf) {
    int col = nf * 16 + (l & 15);
    #pragma unroll
    for (int i = 0; i < 4; ++i) {
      int r = row0 + (l >> 4) * 4 + i;
      if (r < n) xp[(size_t)r * FD + col] = f2bf(acc[nf][i]);
    }
  }
}

// ---------------- MFMA GEMM with fused apply in A-loader ----------------
// A := relu(Ab*svA+tvA) + residA (all bf16 rows); if xout != nullptr, A rows also written back.
// EPI 0: store bf16 A@W.  EPI 2: out[r] = relu(A@W + bias) . head_w + head_b (f32).
template<int EPI>
__global__ __launch_bounds__(256) void mfma_gemm(const unsigned short* __restrict__ Ab,
    const unsigned short* __restrict__ Wtb, void* __restrict__ Cout, int n,
    const float* __restrict__ bias, const float* __restrict__ hw, const float* __restrict__ hb,
    const float* __restrict__ svA, const float* __restrict__ tvA,
    const unsigned short* __restrict__ residA, unsigned short* __restrict__ xout)
{
  __shared__ uint4 bsh[2048];
  const int tid = threadIdx.x;
  const int l = tid & 63;
  const int w = tid >> 6;
  const int row0 = blockIdx.x * 64 + w * 16;

  #pragma unroll
  for (int it = 0; it < 8; ++it) {
    int s = it * 256 + tid;
    int nf = s >> 8, kf = (s >> 6) & 3, sl = s & 63;
    int col = nf * 16 + (sl & 15);
    bsh[s] = *(const uint4*)(Wtb + col * FD + kf * 32 + (sl >> 4) * 8);
  }

  const int arow = row0 + (l & 15);
  bf16x8 a[4];
  if (arow < n) {
    const uint4* agp = (const uint4*)(Ab + (size_t)arow * FD + (l >> 4) * 8);
    const uint4* rsp = (const uint4*)(residA + (size_t)arow * FD + (l >> 4) * 8);
    uint4* xop = xout ? (uint4*)(xout + (size_t)arow * FD + (l >> 4) * 8) : nullptr;
    #pragma unroll
    for (int kf = 0; kf < 4; ++kf) {
      uint4 ag = agp[kf * 4];
      uint4 rs = rsp[kf * 4];
      int cb4 = kf * 8 + (l >> 4) * 2;
      float4 s0 = ((const float4*)svA)[cb4];
      float4 s1 = ((const float4*)svA)[cb4 + 1];
      float4 t0 = ((const float4*)tvA)[cb4];
      float4 t1 = ((const float4*)tvA)[cb4 + 1];
      uint4 pk;
      pk.x = pack_bf2(fmaxf(fmaf(bf_lo(ag.x), s0.x, t0.x), 0.f) + bf_lo(rs.x),
                      fmaxf(fmaf(bf_hi(ag.x), s0.y, t0.y), 0.f) + bf_hi(rs.x));
      pk.y = pack_bf2(fmaxf(fmaf(bf_lo(ag.y), s0.z, t0.z), 0.f) + bf_lo(rs.y),
                      fmaxf(fmaf(bf_hi(ag.y), s0.w, t0.w), 0.f) + bf_hi(rs.y));
      pk.z = pack_bf2(fmaxf(fmaf(bf_lo(ag.z), s1.x, t1.x), 0.f) + bf_lo(rs.z),
                      fmaxf(fmaf(bf_hi(ag.z), s1.y, t1.y), 0.f) + bf_hi(rs.z));
      pk.w = pack_bf2(fmaxf(fmaf(bf_lo(ag.w), s1.z, t1.z), 0.f) + bf_lo(rs.w),
                      fmaxf(fmaf(bf_hi(ag.w), s1.w, t1.w), 0.f) + bf_hi(rs.w));
      a[kf] = *(bf16x8*)&pk;
      if (xop) xop[kf * 4] = pk;
    }
  } else {
    #pragma unroll
    for (int kf = 0; kf < 4; ++kf) a[kf] = (bf16x8)(short)0;
  }

  __syncthreads();

  f32x4 acc[8];
  #pragma unroll
  for (int nf = 0; nf < 8; ++nf) acc[nf] = (f32x4)(0.0f);
  #pragma unroll
  for (int nf = 0; nf < 8; ++nf)
    #pragma unroll
    for (int kf = 0; kf < 4; ++kf) {
      uint4 braw = bsh[(nf * 4 + kf) * 64 + l];
      acc[nf] = __builtin_amdgcn_mfma_f32_16x16x32_bf16(a[kf], *(bf16x8*)&braw, acc[nf], 0, 0, 0);
    }

  if (EPI == 2) {
    float hsum[4] = {0.f, 0.f, 0.f, 0.f};
    #pragma unroll
    for (int nf = 0; nf < 8; ++nf) {
      int col = nf * 16 + (l & 15);
      float bm = bias[col];
      float hwc = hw[col];
      #pragma unroll
      for (int i = 0; i < 4; ++i)
        hsum[i] += fmaxf(acc[nf][i] + bm, 0.f) * hwc;
    }
    #pragma unroll
    for (int i = 0; i < 4; ++i) {
      #pragma unroll
      for (int off = 1; off < 16; off <<= 1) hsum[i] += __shfl_xor(hsum[i], off);
    }
    if ((l & 15) == 0) {
      float hb0 = hb[0];
      #pragma unroll
      for (int i = 0; i < 4; ++i) {
        int r = row0 + (l >> 4) * 4 + i;
        if (r < n) ((float*)Cout)[r] = hsum[i] + hb0;
      }
    }
  } else {
    unsigned short* outp = (unsigned short*)Cout;
    #pragma unroll
    for (int nf = 0; nf < 8; ++nf) {
      int col = nf * 16 + (l & 15);
      #pragma unroll
      for (int i = 0; i < 4; ++i) {
        int r = row0 + (l >> 4) * 4 + i;
        if (r < n) outp[(size_t)r * FD + col] = f2bf(acc[nf][i]);
      }
    }
  }
}

// ---------------- aggregation (bf16 rows) + fused GraphNorm stats ----------------
__device__ __forceinline__ void acc8(float* a, uint4 u, float wn) {
  a[0] = fmaf(wn, bf_lo(u.x), a[0]); a[1] = fmaf(wn, bf_hi(u.x), a[1]);
  a[2] = fmaf(wn, bf_lo(u.y), a[2]); a[3] = fmaf(wn, bf_hi(u.y), a[3]);
  a[4] = fmaf(wn, bf_lo(u.z), a[4]); a[5] = fmaf(wn, bf_hi(u.z), a[5]);
  a[6] = fmaf(wn, bf_lo(u.w), a[6]); a[7] = fmaf(wn, bf_hi(u.w), a[7]);
}

__global__ __launch_bounds__(256) void agg_bf16(const uint4* __restrict__ hw4, uint4* __restrict__ agg4,
    const int* __restrict__ indptr, const int* __restrict__ csr_src, const float* __restrict__ csr_norm,
    const float* __restrict__ dinv, const float* __restrict__ bias,
    float* __restrict__ colsum, float* __restrict__ colsum2, int n)
{
  __shared__ float sredS[4][16][9];
  __shared__ float sredQ[4][16][9];
  const int wv = threadIdx.x >> 6;
  const int lane = threadIdx.x & 63;
  const int q = lane >> 4;
  const int l16 = lane & 15;
  const int gs = blockIdx.x * 16 + wv * 4 + q;
  const int ns = gridDim.x * 16;
  const float4 b0 = ((const float4*)bias)[l16 * 2];
  const float4 b1 = ((const float4*)bias)[l16 * 2 + 1];
  float st[8], sq[8];
  #pragma unroll
  for (int j = 0; j < 8; ++j) { st[j] = 0.f; sq[j] = 0.f; }

  int c = gs;
  float di = 0.f; int e0 = 0, e1 = 0;
  uint4 su = make_uint4(0, 0, 0, 0);
  if (c < n) {
    di = dinv[c];
    e0 = indptr[c]; e1 = indptr[c + 1];
    su = hw4[(size_t)c * 16 + l16];
  }
  while (c < n) {
    const int cn = c + ns;
    float di_n = 0.f; int e0_n = 0, e1_n = 0;
    uint4 su_n = make_uint4(0, 0, 0, 0);
    if (cn < n) {
      di_n = dinv[cn];
      e0_n = indptr[cn]; e1_n = indptr[cn + 1];
      su_n = hw4[(size_t)cn * 16 + l16];
    }

    float self = di * di;
    float a[8];
    a[0] = fmaf(self, bf_lo(su.x), b0.x); a[1] = fmaf(self, bf_hi(su.x), b0.y);
    a[2] = fmaf(self, bf_lo(su.y), b0.z); a[3] = fmaf(self, bf_hi(su.y), b0.w);
    a[4] = fmaf(self, bf_lo(su.z), b1.x); a[5] = fmaf(self, bf_hi(su.z), b1.y);
    a[6] = fmaf(self, bf_lo(su.w), b1.z); a[7] = fmaf(self, bf_hi(su.w), b1.w);
    int e = e0;
    for (; e + 4 <= e1; e += 4) {
      int s0 = csr_src[e], s1 = csr_src[e + 1], s2 = csr_src[e + 2], s3 = csr_src[e + 3];
      float w0 = csr_norm[e], w1 = csr_norm[e + 1], w2 = csr_norm[e + 2], w3 = csr_norm[e + 3];
      uint4 u0 = hw4[(size_t)s0 * 16 + l16];
      uint4 u1 = hw4[(size_t)s1 * 16 + l16];
      uint4 u2 = hw4[(size_t)s2 * 16 + l16];
      uint4 u3 = hw4[(size_t)s3 * 16 + l16];
      acc8(a, u0, w0); acc8(a, u1, w1); acc8(a, u2, w2); acc8(a, u3, w3);
    }
    if (e + 2 <= e1) {
      int s0 = csr_src[e], s1 = csr_src[e + 1];
      float w0 = csr_norm[e], w1 = csr_norm[e + 1];
      uint4 u0 = hw4[(size_t)s0 * 16 + l16];
      uint4 u1 = hw4[(size_t)s1 * 16 + l16];
      acc8(a, u0, w0); acc8(a, u1, w1);
      e += 2;
    }
    if (e < e1) {
      int s0 = csr_src[e];
      float w0 = csr_norm[e];
      uint4 u0 = hw4[(size_t)s0 * 16 + l16];
      acc8(a, u0, w0);
    }
    uint4 o;
    o.x = pack_bf2(a[0], a[1]); o.y = pack_bf2(a[2], a[3]);
    o.z = pack_bf2(a[4], a[5]); o.w = pack_bf2(a[6], a[7]);
    agg4[(size_t)c * 16 + l16] = o;
    #pragma unroll
    for (int j = 0; j < 8; ++j) { st[j] += a[j]; sq[j] += a[j] * a[j]; }

    c = cn; di = di_n; e0 = e0_n; e1 = e1_n; su = su_n;
  }

  #pragma unroll
  for (int j = 0; j < 8; ++j) {
    st[j] += __shfl_xor(st[j], 16); st[j] += __shfl_xor(st[j], 32);
    sq[j] += __shfl_xor(sq[j], 16); sq[j] += __shfl_xor(sq[j], 32);
  }
  if (q == 0) {
    #pragma unroll
    for (int j = 0; j < 8; ++j) { sredS[wv][l16][j] = st[j]; sredQ[wv][l16][j] = sq[j]; }
  }
  __syncthreads();
  int t = threadIdx.x;
  int which = t >> 7, cc = t & 127;
  int rl = cc >> 3, rk = cc & 7;
  float v = 0.f;
  #pragma unroll
  for (int w2 = 0; w2 < 4; ++w2)
    v += which ? sredQ[w2][rl][rk] : sredS[w2][rl][rk];
  atomicAdd(which ? &colsum2[cc] : &colsum[cc], v);
}

// ---------------- GraphNorm scalars ----------------
__global__ void finalize_stats(const float* __restrict__ colsum, const float* __restrict__ colsum2,
    const float* __restrict__ gnw, const float* __restrict__ gnb, const float* __restrict__ ms,
    float* __restrict__ sv, float* __restrict__ tv, float inv_n)
{
  int d = threadIdx.x;
  if (d < FD) {
    float mean = colsum[d] * inv_n;
    float m2 = colsum2[d] * inv_n;
    float m = ms[d];
    float var = m2 - 2.f * m * mean * mean + m * m * mean * mean;
    float s = gnw[d] * rsqrtf(var + 1e-5f);
    sv[d] = s;
    tv[d] = gnb[d] - m * mean * s;
  }
}

// ---------------- launcher ----------------
extern "C" void kernel_launch(void* const* d_in, const int* in_sizes, int n_in,
                              void* d_out, int out_size, void* d_ws, size_t ws_size,
                              hipStream_t stream) {
  const float* x0      = (const float*)d_in[0];
  const int* ei        = (const int*)d_in[1];   // int32 per harness conversion
  const float* conv_w  = (const float*)d_in[2];
  const float* conv_b  = (const float*)d_in[3];
  const float* gn_w    = (const float*)d_in[4];
  const float* gn_b    = (const float*)d_in[5];
  const float* gn_ms   = (const float*)d_in[6];
  const float* proj_w  = (const float*)d_in[7];
  const float* mlp_w   = (const float*)d_in[8];
  const float* mlp_b   = (const float*)d_in[9];
  const float* head_w  = (const float*)d_in[10];
  const float* head_b  = (const float*)d_in[11];
  float* out = (float*)d_out;

  const int n = in_sizes[0] / FD;
  const int e = in_sizes[1] / 2;
  const size_t ND = (size_t)n * FD;

  unsigned short* hwb  = (unsigned short*)d_ws;  // hw per layer
  unsigned short* aggb = hwb + ND;               // agg per layer
  unsigned short* xpb  = aggb + ND;              // xp (x0@proj), later x2
  unsigned short* xrb  = xpb + ND;               // x1
  unsigned short* Wtb  = xrb + ND;               // 5 * 16384 bf16
  float* csr_norm = (float*)(Wtb + 5 * 16384);
  float* dinv     = csr_norm + e;
  float* stats    = dinv + n;                    // colsum[3][128] then colsum2[3][128]
  float* sv       = stats + 768;
  float* tv       = sv + FD;
  int* deg     = (int*)(tv + FD);
  int* fill    = deg + n;
  int* indptr  = fill + n;
  int* tmp     = indptr + (n + 1);
  int* partials= tmp + n;
  int* csr_src = partials + 1024;

  const int nb256_n = (n + 255) / 256;
  const int nb256_e = (e + 255) / 256;
  const int nb128_n = (n + 127) / 128;

  // ---- graph preprocessing ----
  init_kernel<<<nb256_n, 256, 0, stream>>>(deg, fill, stats, n);
  edge_count_kernel<<<nb256_e, 256, 0, stream>>>(ei, e, deg);
  scan1_kernel<<<nb128_n, 128, 0, stream>>>(deg, n, tmp, partials, dinv);
  scan2_kernel<<<1, 1024, 0, stream>>>(partials, nb128_n);
  scan3_kernel<<<nb128_n, 128, 0, stream>>>(tmp, partials, indptr, n);
  fill_kernel<<<nb256_e, 256, 0, stream>>>(ei, e, indptr, fill, dinv, csr_src, csr_norm);

  // ---- bf16 weight prep ----
  prep_w<<<320, 256, 0, stream>>>(conv_w, proj_w, mlp_w, Wtb);

  const int gemm_grid = (n + 63) / 64;
  const float inv_n = 1.f / (float)n;
  const unsigned short* Wt_conv0 = Wtb;
  const unsigned short* Wt_conv1 = Wtb + 16384;
  const unsigned short* Wt_conv2 = Wtb + 2 * 16384;
  const unsigned short* Wt_proj  = Wtb + 3 * 16384;
  const unsigned short* Wt_mlp   = Wtb + 4 * 16384;

  // ---- layer 0: hw0 = x0@W0 and xp = x0@proj in one kernel (f32 A inline-converted) ----
  gemm_dual<<<gemm_grid, 256, 0, stream>>>(x0, Wt_conv0, Wt_proj, hwb, xpb, n);
  agg_bf16<<<2048, 256, 0, stream>>>((const uint4*)hwb, (uint4*)aggb, indptr, csr_src, csr_norm, dinv,
                                     conv_b + 0 * FD, stats + 0 * FD, stats + 384 + 0 * FD, n);
  finalize_stats<<<1, 128, 0, stream>>>(stats + 0 * FD, stats + 384 + 0 * FD,
      gn_w + 0 * FD, gn_b + 0 * FD, gn_ms + 0 * FD, sv, tv, inv_n);

  // ---- layer 1: A = x1 = relu(agg0*s0+t0)+xp (written to xrb), C = hw1 ----
  mfma_gemm<0><<<gemm_grid, 256, 0, stream>>>(aggb, Wt_conv1, hwb, n,
      nullptr, nullptr, nullptr, sv, tv, xpb, xrb);
  agg_bf16<<<2048, 256, 0, stream>>>((const uint4*)hwb, (uint4*)aggb, indptr, csr_src, csr_norm, dinv,
                                     conv_b + 1 * FD, stats + 1 * FD, stats + 384 + 1 * FD, n);
  finalize_stats<<<1, 128, 0, stream>>>(stats + 1 * FD, stats + 384 + 1 * FD,
      gn_w + 1 * FD, gn_b + 1 * FD, gn_ms + 1 * FD, sv, tv, inv_n);

  // ---- layer 2: A = x2 = relu(agg1*s1+t1)+x1 (written to xpb), C = hw2 ----
  mfma_gemm<0><<<gemm_grid, 256, 0, stream>>>(aggb, Wt_conv2, hwb, n,
      nullptr, nullptr, nullptr, sv, tv, xrb, xpb);
  agg_bf16<<<2048, 256, 0, stream>>>((const uint4*)hwb, (uint4*)aggb, indptr, csr_src, csr_norm, dinv,
                                     conv_b + 2 * FD, stats + 2 * FD, stats + 384 + 2 * FD, n);
  finalize_stats<<<1, 128, 0, stream>>>(stats + 2 * FD, stats + 384 + 2 * FD,
      gn_w + 2 * FD, gn_b + 2 * FD, gn_ms + 2 * FD, sv, tv, inv_n);

  // ---- MLP + head: A = x3 = relu(agg2*s2+t2)+x2 inline, f32 out ----
  mfma_gemm<2><<<gemm_grid, 256, 0, stream>>>(aggb, Wt_mlp, out, n,
      mlp_b, head_w, head_b, sv, tv, xpb, nullptr);
}

// Round 10
// 399.931 us; speedup vs baseline: 1.8958x; 1.0026x over previous
//
#include <hip/hip_runtime.h>

#define FD 128

typedef __attribute__((ext_vector_type(8))) short bf16x8;
typedef __attribute__((ext_vector_type(4))) float f32x4;

__device__ __forceinline__ unsigned short f2bf(float f) {
  unsigned int u = __float_as_uint(f);
  unsigned int r = (u + 0x7fffu + ((u >> 16) & 1u)) >> 16;
  return (unsigned short)r;
}
__device__ __forceinline__ float bf_lo(unsigned int u) { return __uint_as_float(u << 16); }
__device__ __forceinline__ float bf_hi(unsigned int u) { return __uint_as_float(u & 0xffff0000u); }
__device__ __forceinline__ unsigned int pack_bf2(float a, float b) {
  return (unsigned int)f2bf(a) | ((unsigned int)f2bf(b) << 16);
}

// ---------------- graph preprocessing ----------------
__global__ __launch_bounds__(256) void init_kernel(int* __restrict__ deg, int* __restrict__ fill,
    float* __restrict__ stats, int n) {
  int i = blockIdx.x * 256 + threadIdx.x;
  if (i < n) { deg[i] = 1; fill[i] = 0; }
  if (i < 768) stats[i] = 0.f;   // colsum[3][128] + colsum2[3][128]
}

__global__ __launch_bounds__(256) void edge_count_kernel(const int* __restrict__ ei, int e, int* __restrict__ deg) {
  int i = blockIdx.x * 256 + threadIdx.x;
  if (i < e) atomicAdd(&deg[ei[e + i]], 1);
}

// scan over (deg-1) to get CSR edge offsets; also emits dinv = rsqrt(deg)
__global__ __launch_bounds__(128) void scan1_kernel(const int* __restrict__ deg, int n,
    int* __restrict__ tmp, int* __restrict__ partials, float* __restrict__ dinv) {
  __shared__ int s[128];
  int b = blockIdx.x, t = threadIdx.x;
  int i = b * 128 + t;
  int d = (i < n) ? deg[i] : 1;
  if (i < n) dinv[i] = rsqrtf((float)d);
  s[t] = (i < n) ? (d - 1) : 0;
  __syncthreads();
  for (int off = 1; off < 128; off <<= 1) {
    int u = (t >= off) ? s[t - off] : 0;
    __syncthreads();
    s[t] += u;
    __syncthreads();
  }
  if (i < n) tmp[i] = s[t];
  if (t == 127) partials[b] = s[127];
}

__global__ __launch_bounds__(1024) void scan2_kernel(int* __restrict__ partials, int nb) {
  __shared__ int s[1024];
  int t = threadIdx.x;
  s[t] = (t < nb) ? partials[t] : 0;
  __syncthreads();
  for (int off = 1; off < 1024; off <<= 1) {
    int u = (t >= off) ? s[t - off] : 0;
    __syncthreads();
    s[t] += u;
    __syncthreads();
  }
  if (t < nb) partials[t] = (t == 0) ? 0 : s[t - 1];
}

__global__ __launch_bounds__(128) void scan3_kernel(const int* __restrict__ tmp, const int* __restrict__ partials, int* __restrict__ indptr, int n) {
  int i = blockIdx.x * 128 + threadIdx.x;
  if (i < n) indptr[i + 1] = tmp[i] + partials[blockIdx.x];
  if (i == 0) indptr[0] = 0;
}

__global__ __launch_bounds__(256) void fill_kernel(const int* __restrict__ ei, int e,
    const int* __restrict__ indptr, int* __restrict__ fill, const float* __restrict__ dinv,
    int* __restrict__ csr_src, float* __restrict__ csr_norm) {
  int i = blockIdx.x * 256 + threadIdx.x;
  if (i < e) {
    int r = ei[i];
    int c = ei[e + i];
    int pos = indptr[c] + atomicAdd(&fill[c], 1);
    csr_src[pos] = r;
    csr_norm[pos] = dinv[r] * dinv[c];
  }
}

// ---------------- edge-balanced stream partition ----------------
// rowstart[s] = smallest r with indptr[r]+2r >= total*s/S  (f strictly increasing)
__global__ __launch_bounds__(256) void balance_kernel(const int* __restrict__ indptr, int n, int S,
    int* __restrict__ rowstart) {
  int s = blockIdx.x * 256 + threadIdx.x;
  if (s > S) return;
  long long total = (long long)indptr[n] + 2LL * n;
  long long target = (total * s) / S;
  int lo = 0, hi = n;
  while (lo < hi) {
    int mid = (lo + hi) >> 1;
    long long f = (long long)indptr[mid] + 2LL * mid;
    if (f >= target) hi = mid; else lo = mid + 1;
  }
  rowstart[s] = lo;
}

// ---------------- weight prep: Wt[m][col][k] = W[m][k][col] as bf16 ----------------
__global__ __launch_bounds__(256) void prep_w(const float* __restrict__ conv_w, const float* __restrict__ proj_w,
    const float* __restrict__ mlp_w, unsigned short* __restrict__ Wtb) {
  int idx = blockIdx.x * 256 + threadIdx.x;   // 5*16384 total
  int m = idx >> 14;
  int o = idx & 16383;
  int col = o >> 7, k = o & 127;
  const float* src = (m < 3) ? (conv_w + m * 16384) : ((m == 3) ? proj_w : mlp_w);
  Wtb[idx] = f2bf(src[k * FD + col]);
}

// ---------------- layer-0 dual GEMM: hw0 = x0@W0, xp = x0@P (A loaded once from f32) ----------------
__global__ __launch_bounds__(256) void gemm_dual(const float* __restrict__ x0,
    const unsigned short* __restrict__ W0t, const unsigned short* __restrict__ Pt,
    unsigned short* __restrict__ hw0, unsigned short* __restrict__ xp, int n)
{
  __shared__ uint4 bsh[2048];   // 32 KB, fragment-major: slot (nf*4+kf)*64 + lane
  const int tid = threadIdx.x;
  const int l = tid & 63;
  const int w = tid >> 6;
  const int row0 = blockIdx.x * 64 + w * 16;

  #pragma unroll
  for (int it = 0; it < 8; ++it) {
    int s = it * 256 + tid;
    int nf = s >> 8, kf = (s >> 6) & 3, sl = s & 63;
    int col = nf * 16 + (sl & 15);
    bsh[s] = *(const uint4*)(W0t + col * FD + kf * 32 + (sl >> 4) * 8);
  }

  const int arow = row0 + (l & 15);
  bf16x8 a[4];
  if (arow < n) {
    const float4* ap = (const float4*)(x0 + (size_t)arow * FD + (l >> 4) * 8);
    #pragma unroll
    for (int kf = 0; kf < 4; ++kf) {
      float4 f0 = ap[kf * 8];
      float4 f1 = ap[kf * 8 + 1];
      uint4 pk;
      pk.x = pack_bf2(f0.x, f0.y); pk.y = pack_bf2(f0.z, f0.w);
      pk.z = pack_bf2(f1.x, f1.y); pk.w = pack_bf2(f1.z, f1.w);
      a[kf] = *(bf16x8*)&pk;
    }
  } else {
    #pragma unroll
    for (int kf = 0; kf < 4; ++kf) a[kf] = (bf16x8)(short)0;
  }

  __syncthreads();

  f32x4 acc[8];
  #pragma unroll
  for (int nf = 0; nf < 8; ++nf) acc[nf] = (f32x4)(0.0f);
  #pragma unroll
  for (int nf = 0; nf < 8; ++nf)
    #pragma unroll
    for (int kf = 0; kf < 4; ++kf) {
      uint4 braw = bsh[(nf * 4 + kf) * 64 + l];
      acc[nf] = __builtin_amdgcn_mfma_f32_16x16x32_bf16(a[kf], *(bf16x8*)&braw, acc[nf], 0, 0, 0);
    }

  __syncthreads();   // all waves done reading W0

  #pragma unroll
  for (int it = 0; it < 8; ++it) {
    int s = it * 256 + tid;
    int nf = s >> 8, kf = (s >> 6) & 3, sl = s & 63;
    int col = nf * 16 + (sl & 15);
    bsh[s] = *(const uint4*)(Pt + col * FD + kf * 32 + (sl >> 4) * 8);
  }
  #pragma unroll
  for (int nf = 0; nf < 8; ++nf) {
    int col = nf * 16 + (l & 15);
    #pragma unroll
    for (int i = 0; i < 4; ++i) {
      int r = row0 + (l >> 4) * 4 + i;
      if (r < n) hw0[(size_t)r * FD + col] = f2bf(acc[nf][i]);
    }
  }

  __syncthreads();

  #pragma unroll
  for (int nf = 0; nf < 8; ++nf) acc[nf] = (f32x4)(0.0f);
  #pragma unroll
  for (int nf = 0; nf < 8; ++nf)
    #pragma unroll
    for (int kf = 0; kf < 4; ++kf) {
      uint4 braw = bsh[(nf * 4 + kf) * 64 + l];
      acc[nf] = __builtin_amdgcn_mfma_f32_16x16x32_bf16(a[kf], *(bf16x8*)&braw, acc[nf], 0, 0, 0);
    }
  #pragma unroll
  for (int nf = 0; nf < 8; ++nf) {
    int col = nf * 16 + (l & 15);
    #pragma unroll
    for (int i = 0; i < 4; ++i) {
      int r = row0 + (l >> 4) * 4 + i;
      if (r < n) xp[(size_t)r * FD + col] = f2bf(acc[nf][i]);
    }
  }
}

// ---------------- MFMA GEMM with fused GraphNorm-finalize + apply in A-loader ----------------
// sv/tv computed per block from colsum/colsum2 (finalize fused); A := relu(Ab*sv+tv)+residA;
// if xout != nullptr, A rows also written back.
// EPI 0: store bf16 A@W.  EPI 2: out[r] = relu(A@W + bias) . head_w + head_b (f32).
template<int EPI>
__global__ __launch_bounds__(256) void mfma_gemm(const unsigned short* __restrict__ Ab,
    const unsigned short* __restrict__ Wtb, void* __restrict__ Cout, int n,
    const float* __restrict__ bias, const float* __restrict__ hw, const float* __restrict__ hb,
    const float* __restrict__ colsum, const float* __restrict__ colsum2,
    const float* __restrict__ gnw, const float* __restrict__ gnb, const float* __restrict__ gnms,
    float inv_n, const unsigned short* __restrict__ residA, unsigned short* __restrict__ xout)
{
  __shared__ uint4 bsh[2048];
  __shared__ __align__(16) float svs[128];
  __shared__ __align__(16) float tvs[128];
  const int tid = threadIdx.x;
  const int l = tid & 63;
  const int w = tid >> 6;
  const int row0 = blockIdx.x * 64 + w * 16;

  #pragma unroll
  for (int it = 0; it < 8; ++it) {
    int s = it * 256 + tid;
    int nf = s >> 8, kf = (s >> 6) & 3, sl = s & 63;
    int col = nf * 16 + (sl & 15);
    bsh[s] = *(const uint4*)(Wtb + col * FD + kf * 32 + (sl >> 4) * 8);
  }
  if (tid < 128) {
    float mean = colsum[tid] * inv_n;
    float m2 = colsum2[tid] * inv_n;
    float m = gnms[tid];
    float var = m2 - 2.f * m * mean * mean + m * m * mean * mean;
    float sc = gnw[tid] * rsqrtf(var + 1e-5f);
    svs[tid] = sc;
    tvs[tid] = gnb[tid] - m * mean * sc;
  }
  __syncthreads();

  const int arow = row0 + (l & 15);
  bf16x8 a[4];
  if (arow < n) {
    const uint4* agp = (const uint4*)(Ab + (size_t)arow * FD + (l >> 4) * 8);
    const uint4* rsp = (const uint4*)(residA + (size_t)arow * FD + (l >> 4) * 8);
    uint4* xop = xout ? (uint4*)(xout + (size_t)arow * FD + (l >> 4) * 8) : nullptr;
    #pragma unroll
    for (int kf = 0; kf < 4; ++kf) {
      uint4 ag = agp[kf * 4];
      uint4 rs = rsp[kf * 4];
      int cb4 = kf * 8 + (l >> 4) * 2;
      float4 s0 = ((const float4*)svs)[cb4];
      float4 s1 = ((const float4*)svs)[cb4 + 1];
      float4 t0 = ((const float4*)tvs)[cb4];
      float4 t1 = ((const float4*)tvs)[cb4 + 1];
      uint4 pk;
      pk.x = pack_bf2(fmaxf(fmaf(bf_lo(ag.x), s0.x, t0.x), 0.f) + bf_lo(rs.x),
                      fmaxf(fmaf(bf_hi(ag.x), s0.y, t0.y), 0.f) + bf_hi(rs.x));
      pk.y = pack_bf2(fmaxf(fmaf(bf_lo(ag.y), s0.z, t0.z), 0.f) + bf_lo(rs.y),
                      fmaxf(fmaf(bf_hi(ag.y), s0.w, t0.w), 0.f) + bf_hi(rs.y));
      pk.z = pack_bf2(fmaxf(fmaf(bf_lo(ag.z), s1.x, t1.x), 0.f) + bf_lo(rs.z),
                      fmaxf(fmaf(bf_hi(ag.z), s1.y, t1.y), 0.f) + bf_hi(rs.z));
      pk.w = pack_bf2(fmaxf(fmaf(bf_lo(ag.w), s1.z, t1.z), 0.f) + bf_lo(rs.w),
                      fmaxf(fmaf(bf_hi(ag.w), s1.w, t1.w), 0.f) + bf_hi(rs.w));
      a[kf] = *(bf16x8*)&pk;
      if (xop) xop[kf * 4] = pk;
    }
  } else {
    #pragma unroll
    for (int kf = 0; kf < 4; ++kf) a[kf] = (bf16x8)(short)0;
  }

  __syncthreads();

  f32x4 acc[8];
  #pragma unroll
  for (int nf = 0; nf < 8; ++nf) acc[nf] = (f32x4)(0.0f);
  #pragma unroll
  for (int nf = 0; nf < 8; ++nf)
    #pragma unroll
    for (int kf = 0; kf < 4; ++kf) {
      uint4 braw = bsh[(nf * 4 + kf) * 64 + l];
      acc[nf] = __builtin_amdgcn_mfma_f32_16x16x32_bf16(a[kf], *(bf16x8*)&braw, acc[nf], 0, 0, 0);
    }

  if (EPI == 2) {
    float hsum[4] = {0.f, 0.f, 0.f, 0.f};
    #pragma unroll
    for (int nf = 0; nf < 8; ++nf) {
      int col = nf * 16 + (l & 15);
      float bm = bias[col];
      float hwc = hw[col];
      #pragma unroll
      for (int i = 0; i < 4; ++i)
        hsum[i] += fmaxf(acc[nf][i] + bm, 0.f) * hwc;
    }
    #pragma unroll
    for (int i = 0; i < 4; ++i) {
      #pragma unroll
      for (int off = 1; off < 16; off <<= 1) hsum[i] += __shfl_xor(hsum[i], off);
    }
    if ((l & 15) == 0) {
      float hb0 = hb[0];
      #pragma unroll
      for (int i = 0; i < 4; ++i) {
        int r = row0 + (l >> 4) * 4 + i;
        if (r < n) ((float*)Cout)[r] = hsum[i] + hb0;
      }
    }
  } else {
    unsigned short* outp = (unsigned short*)Cout;
    #pragma unroll
    for (int nf = 0; nf < 8; ++nf) {
      int col = nf * 16 + (l & 15);
      #pragma unroll
      for (int i = 0; i < 4; ++i) {
        int r = row0 + (l >> 4) * 4 + i;
        if (r < n) outp[(size_t)r * FD + col] = f2bf(acc[nf][i]);
      }
    }
  }
}

// ---------------- aggregation (bf16 rows) + fused GraphNorm stats ----------------
// Edge-balanced: stream s (quarter-wave, 16 lanes x uint4 = full 256B row) owns contiguous
// rows [rowstart[s], rowstart[s+1]) with ~equal edges+2*rows cost. Pipelined header prefetch.
__device__ __forceinline__ void acc8(float* a, uint4 u, float wn) {
  a[0] = fmaf(wn, bf_lo(u.x), a[0]); a[1] = fmaf(wn, bf_hi(u.x), a[1]);
  a[2] = fmaf(wn, bf_lo(u.y), a[2]); a[3] = fmaf(wn, bf_hi(u.y), a[3]);
  a[4] = fmaf(wn, bf_lo(u.z), a[4]); a[5] = fmaf(wn, bf_hi(u.z), a[5]);
  a[6] = fmaf(wn, bf_lo(u.w), a[6]); a[7] = fmaf(wn, bf_hi(u.w), a[7]);
}

__global__ __launch_bounds__(256) void agg_bf16(const uint4* __restrict__ hw4, uint4* __restrict__ agg4,
    const int* __restrict__ indptr, const int* __restrict__ csr_src, const float* __restrict__ csr_norm,
    const float* __restrict__ dinv, const float* __restrict__ bias,
    float* __restrict__ colsum, float* __restrict__ colsum2,
    const int* __restrict__ rowstart, int n)
{
  __shared__ float sredS[4][16][9];
  __shared__ float sredQ[4][16][9];
  const int wv = threadIdx.x >> 6;
  const int lane = threadIdx.x & 63;
  const int q = lane >> 4;
  const int l16 = lane & 15;
  const int sid = blockIdx.x * 16 + wv * 4 + q;
  const float4 b0 = ((const float4*)bias)[l16 * 2];
  const float4 b1 = ((const float4*)bias)[l16 * 2 + 1];
  float st[8], sq[8];
  #pragma unroll
  for (int j = 0; j < 8; ++j) { st[j] = 0.f; sq[j] = 0.f; }

  int c = rowstart[sid];
  const int cend = rowstart[sid + 1];
  float di = 0.f; int e0 = 0, e1 = 0;
  uint4 su = make_uint4(0, 0, 0, 0);
  if (c < cend) {
    di = dinv[c];
    e0 = indptr[c]; e1 = indptr[c + 1];
    su = hw4[(size_t)c * 16 + l16];
  }
  while (c < cend) {
    const int cn = c + 1;
    float di_n = 0.f; int e1_n = 0;
    uint4 su_n = make_uint4(0, 0, 0, 0);
    if (cn < cend) {
      di_n = dinv[cn];
      e1_n = indptr[cn + 1];          // e0(c+1) == e1(c), contiguous
      su_n = hw4[(size_t)cn * 16 + l16];
    }

    float self = di * di;
    float a[8];
    a[0] = fmaf(self, bf_lo(su.x), b0.x); a[1] = fmaf(self, bf_hi(su.x), b0.y);
    a[2] = fmaf(self, bf_lo(su.y), b0.z); a[3] = fmaf(self, bf_hi(su.y), b0.w);
    a[4] = fmaf(self, bf_lo(su.z), b1.x); a[5] = fmaf(self, bf_hi(su.z), b1.y);
    a[6] = fmaf(self, bf_lo(su.w), b1.z); a[7] = fmaf(self, bf_hi(su.w), b1.w);
    int e = e0;
    for (; e + 4 <= e1; e += 4) {
      int s0 = csr_src[e], s1 = csr_src[e + 1], s2 = csr_src[e + 2], s3 = csr_src[e + 3];
      float w0 = csr_norm[e], w1 = csr_norm[e + 1], w2 = csr_norm[e + 2], w3 = csr_norm[e + 3];
      uint4 u0 = hw4[(size_t)s0 * 16 + l16];
      uint4 u1 = hw4[(size_t)s1 * 16 + l16];
      uint4 u2 = hw4[(size_t)s2 * 16 + l16];
      uint4 u3 = hw4[(size_t)s3 * 16 + l16];
      acc8(a, u0, w0); acc8(a, u1, w1); acc8(a, u2, w2); acc8(a, u3, w3);
    }
    if (e + 2 <= e1) {
      int s0 = csr_src[e], s1 = csr_src[e + 1];
      float w0 = csr_norm[e], w1 = csr_norm[e + 1];
      uint4 u0 = hw4[(size_t)s0 * 16 + l16];
      uint4 u1 = hw4[(size_t)s1 * 16 + l16];
      acc8(a, u0, w0); acc8(a, u1, w1);
      e += 2;
    }
    if (e < e1) {
      int s0 = csr_src[e];
      float w0 = csr_norm[e];
      uint4 u0 = hw4[(size_t)s0 * 16 + l16];
      acc8(a, u0, w0);
    }
    uint4 o;
    o.x = pack_bf2(a[0], a[1]); o.y = pack_bf2(a[2], a[3]);
    o.z = pack_bf2(a[4], a[5]); o.w = pack_bf2(a[6], a[7]);
    agg4[(size_t)c * 16 + l16] = o;
    #pragma unroll
    for (int j = 0; j < 8; ++j) { st[j] += a[j]; sq[j] += a[j] * a[j]; }

    c = cn; di = di_n; e0 = e1; e1 = e1_n; su = su_n;
  }

  #pragma unroll
  for (int j = 0; j < 8; ++j) {
    st[j] += __shfl_xor(st[j], 16); st[j] += __shfl_xor(st[j], 32);
    sq[j] += __shfl_xor(sq[j], 16); sq[j] += __shfl_xor(sq[j], 32);
  }
  if (q == 0) {
    #pragma unroll
    for (int j = 0; j < 8; ++j) { sredS[wv][l16][j] = st[j]; sredQ[wv][l16][j] = sq[j]; }
  }
  __syncthreads();
  int t = threadIdx.x;
  int which = t >> 7, cc = t & 127;
  int rl = cc >> 3, rk = cc & 7;
  float v = 0.f;
  #pragma unroll
  for (int w2 = 0; w2 < 4; ++w2)
    v += which ? sredQ[w2][rl][rk] : sredS[w2][rl][rk];
  atomicAdd(which ? &colsum2[cc] : &colsum[cc], v);
}

// ---------------- launcher ----------------
extern "C" void kernel_launch(void* const* d_in, const int* in_sizes, int n_in,
                              void* d_out, int out_size, void* d_ws, size_t ws_size,
                              hipStream_t stream) {
  const float* x0      = (const float*)d_in[0];
  const int* ei        = (const int*)d_in[1];   // int32 per harness conversion
  const float* conv_w  = (const float*)d_in[2];
  const float* conv_b  = (const float*)d_in[3];
  const float* gn_w    = (const float*)d_in[4];
  const float* gn_b    = (const float*)d_in[5];
  const float* gn_ms   = (const float*)d_in[6];
  const float* proj_w  = (const float*)d_in[7];
  const float* mlp_w   = (const float*)d_in[8];
  const float* mlp_b   = (const float*)d_in[9];
  const float* head_w  = (const float*)d_in[10];
  const float* head_b  = (const float*)d_in[11];
  float* out = (float*)d_out;

  const int n = in_sizes[0] / FD;
  const int e = in_sizes[1] / 2;
  const size_t ND = (size_t)n * FD;
  const int AGG_BLOCKS = 2048;
  const int NSTREAMS = AGG_BLOCKS * 16;

  unsigned short* hwb  = (unsigned short*)d_ws;  // hw per layer
  unsigned short* aggb = hwb + ND;               // agg per layer
  unsigned short* xpb  = aggb + ND;              // xp (x0@proj), later x2
  unsigned short* xrb  = xpb + ND;               // x1
  unsigned short* Wtb  = xrb + ND;               // 5 * 16384 bf16
  float* csr_norm = (float*)(Wtb + 5 * 16384);
  float* dinv     = csr_norm + e;
  float* stats    = dinv + n;                    // colsum[3][128] then colsum2[3][128]
  int* deg      = (int*)(stats + 768);
  int* fill     = deg + n;
  int* indptr   = fill + n;
  int* tmp      = indptr + (n + 1);
  int* partials = tmp + n;
  int* rowstart = partials + 1024;
  int* csr_src  = rowstart + (NSTREAMS + 1);

  const int nb256_n = (n + 255) / 256;
  const int nb256_e = (e + 255) / 256;
  const int nb128_n = (n + 127) / 128;

  // ---- graph preprocessing ----
  init_kernel<<<nb256_n, 256, 0, stream>>>(deg, fill, stats, n);
  edge_count_kernel<<<nb256_e, 256, 0, stream>>>(ei, e, deg);
  scan1_kernel<<<nb128_n, 128, 0, stream>>>(deg, n, tmp, partials, dinv);
  scan2_kernel<<<1, 1024, 0, stream>>>(partials, nb128_n);
  scan3_kernel<<<nb128_n, 128, 0, stream>>>(tmp, partials, indptr, n);
  fill_kernel<<<nb256_e, 256, 0, stream>>>(ei, e, indptr, fill, dinv, csr_src, csr_norm);
  balance_kernel<<<(NSTREAMS + 256) / 256, 256, 0, stream>>>(indptr, n, NSTREAMS, rowstart);

  // ---- bf16 weight prep ----
  prep_w<<<320, 256, 0, stream>>>(conv_w, proj_w, mlp_w, Wtb);

  const int gemm_grid = (n + 63) / 64;
  const float inv_n = 1.f / (float)n;
  const unsigned short* Wt_conv0 = Wtb;
  const unsigned short* Wt_conv1 = Wtb + 16384;
  const unsigned short* Wt_conv2 = Wtb + 2 * 16384;
  const unsigned short* Wt_proj  = Wtb + 3 * 16384;
  const unsigned short* Wt_mlp   = Wtb + 4 * 16384;

  // ---- layer 0: hw0 = x0@W0 and xp = x0@proj in one kernel ----
  gemm_dual<<<gemm_grid, 256, 0, stream>>>(x0, Wt_conv0, Wt_proj, hwb, xpb, n);
  agg_bf16<<<AGG_BLOCKS, 256, 0, stream>>>((const uint4*)hwb, (uint4*)aggb, indptr, csr_src, csr_norm, dinv,
      conv_b + 0 * FD, stats + 0 * FD, stats + 384 + 0 * FD, rowstart, n);

  // ---- layer 1: A = x1 = relu(agg0*s0+t0)+xp (finalize fused), writes x1 -> xrb, C = hw1 ----
  mfma_gemm<0><<<gemm_grid, 256, 0, stream>>>(aggb, Wt_conv1, hwb, n,
      nullptr, nullptr, nullptr, stats + 0 * FD, stats + 384 + 0 * FD,
      gn_w + 0 * FD, gn_b + 0 * FD, gn_ms + 0 * FD, inv_n, xpb, xrb);
  agg_bf16<<<AGG_BLOCKS, 256, 0, stream>>>((const uint4*)hwb, (uint4*)aggb, indptr, csr_src, csr_norm, dinv,
      conv_b + 1 * FD, stats + 1 * FD, stats + 384 + 1 * FD, rowstart, n);

  // ---- layer 2: A = x2 = relu(agg1*s1+t1)+x1, writes x2 -> xpb, C = hw2 ----
  mfma_gemm<0><<<gemm_grid, 256, 0, stream>>>(aggb, Wt_conv2, hwb, n,
      nullptr, nullptr, nullptr, stats + 1 * FD, stats + 384 + 1 * FD,
      gn_w + 1 * FD, gn_b + 1 * FD, gn_ms + 1 * FD, inv_n, xrb, xpb);
  agg_bf16<<<AGG_BLOCKS, 256, 0, stream>>>((const uint4*)hwb, (uint4*)aggb, indptr, csr_src, csr_norm, dinv,
      conv_b + 2 * FD, stats + 2 * FD, stats + 384 + 2 * FD, rowstart, n);

  // ---- MLP + head: A = x3 = relu(agg2*s2+t2)+x2 inline, f32 out ----
  mfma_gemm<2><<<gemm_grid, 256, 0, stream>>>(aggb, Wt_mlp, out, n,
      mlp_b, head_w, head_b, stats + 2 * FD, stats + 384 + 2 * FD,
      gn_w + 2 * FD, gn_b + 2 * FD, gn_ms + 2 * FD, inv_n, xpb, nullptr);
}

// Round 11
// 392.668 us; speedup vs baseline: 1.9309x; 1.0185x over previous
//
#include <hip/hip_runtime.h>

#define FD 128

typedef __attribute__((ext_vector_type(8))) short bf16x8;
typedef __attribute__((ext_vector_type(4))) float f32x4;
typedef __attribute__((ext_vector_type(4))) unsigned int uint4v;

__device__ __forceinline__ unsigned short f2bf(float f) {
  unsigned int u = __float_as_uint(f);
  unsigned int r = (u + 0x7fffu + ((u >> 16) & 1u)) >> 16;
  return (unsigned short)r;
}
__device__ __forceinline__ float bf_lo(unsigned int u) { return __uint_as_float(u << 16); }
__device__ __forceinline__ float bf_hi(unsigned int u) { return __uint_as_float(u & 0xffff0000u); }
__device__ __forceinline__ unsigned int pack_bf2(float a, float b) {
  return (unsigned int)f2bf(a) | ((unsigned int)f2bf(b) << 16);
}

// ---------------- graph preprocessing ----------------
__global__ __launch_bounds__(256) void init_kernel(int* __restrict__ deg, int* __restrict__ fill,
    float* __restrict__ stats, int n) {
  int i = blockIdx.x * 256 + threadIdx.x;
  if (i < n) { deg[i] = 1; fill[i] = 0; }
  if (i < 768) stats[i] = 0.f;   // colsum[3][128] + colsum2[3][128]
}

__global__ __launch_bounds__(256) void edge_count_kernel(const int* __restrict__ ei, int e, int* __restrict__ deg) {
  int i = blockIdx.x * 256 + threadIdx.x;
  if (i < e) atomicAdd(&deg[ei[e + i]], 1);
}

// scan over (deg-1) to get CSR edge offsets; also emits dinv = rsqrt(deg)
__global__ __launch_bounds__(128) void scan1_kernel(const int* __restrict__ deg, int n,
    int* __restrict__ tmp, int* __restrict__ partials, float* __restrict__ dinv) {
  __shared__ int s[128];
  int b = blockIdx.x, t = threadIdx.x;
  int i = b * 128 + t;
  int d = (i < n) ? deg[i] : 1;
  if (i < n) dinv[i] = rsqrtf((float)d);
  s[t] = (i < n) ? (d - 1) : 0;
  __syncthreads();
  for (int off = 1; off < 128; off <<= 1) {
    int u = (t >= off) ? s[t - off] : 0;
    __syncthreads();
    s[t] += u;
    __syncthreads();
  }
  if (i < n) tmp[i] = s[t];
  if (t == 127) partials[b] = s[127];
}

__global__ __launch_bounds__(1024) void scan2_kernel(int* __restrict__ partials, int nb) {
  __shared__ int s[1024];
  int t = threadIdx.x;
  s[t] = (t < nb) ? partials[t] : 0;
  __syncthreads();
  for (int off = 1; off < 1024; off <<= 1) {
    int u = (t >= off) ? s[t - off] : 0;
    __syncthreads();
    s[t] += u;
    __syncthreads();
  }
  if (t < nb) partials[t] = (t == 0) ? 0 : s[t - 1];
}

__global__ __launch_bounds__(128) void scan3_kernel(const int* __restrict__ tmp, const int* __restrict__ partials, int* __restrict__ indptr, int n) {
  int i = blockIdx.x * 128 + threadIdx.x;
  if (i < n) indptr[i + 1] = tmp[i] + partials[blockIdx.x];
  if (i == 0) indptr[0] = 0;
}

__global__ __launch_bounds__(256) void fill_kernel(const int* __restrict__ ei, int e,
    const int* __restrict__ indptr, int* __restrict__ fill, const float* __restrict__ dinv,
    int* __restrict__ csr_src, float* __restrict__ csr_norm) {
  int i = blockIdx.x * 256 + threadIdx.x;
  if (i < e) {
    int r = ei[i];
    int c = ei[e + i];
    int pos = indptr[c] + atomicAdd(&fill[c], 1);
    csr_src[pos] = r;
    csr_norm[pos] = dinv[r] * dinv[c];
  }
}

// ---------------- weight prep: Wt[m][col][k] = W[m][k][col] as bf16 ----------------
__global__ __launch_bounds__(256) void prep_w(const float* __restrict__ conv_w, const float* __restrict__ proj_w,
    const float* __restrict__ mlp_w, unsigned short* __restrict__ Wtb) {
  int idx = blockIdx.x * 256 + threadIdx.x;   // 5*16384 total
  int m = idx >> 14;
  int o = idx & 16383;
  int col = o >> 7, k = o & 127;
  const float* src = (m < 3) ? (conv_w + m * 16384) : ((m == 3) ? proj_w : mlp_w);
  Wtb[idx] = f2bf(src[k * FD + col]);
}

// ---------------- layer-0 dual GEMM: hw0 = x0@W0, xp = x0@P (A loaded once from f32) ----------------
__global__ __launch_bounds__(256) void gemm_dual(const float* __restrict__ x0,
    const unsigned short* __restrict__ W0t, const unsigned short* __restrict__ Pt,
    unsigned short* __restrict__ hw0, unsigned short* __restrict__ xp, int n)
{
  __shared__ uint4 bsh[2048];   // 32 KB, fragment-major: slot (nf*4+kf)*64 + lane
  const int tid = threadIdx.x;
  const int l = tid & 63;
  const int w = tid >> 6;
  const int row0 = blockIdx.x * 64 + w * 16;

  #pragma unroll
  for (int it = 0; it < 8; ++it) {
    int s = it * 256 + tid;
    int nf = s >> 8, kf = (s >> 6) & 3, sl = s & 63;
    int col = nf * 16 + (sl & 15);
    bsh[s] = *(const uint4*)(W0t + col * FD + kf * 32 + (sl >> 4) * 8);
  }

  const int arow = row0 + (l & 15);
  bf16x8 a[4];
  if (arow < n) {
    const float4* ap = (const float4*)(x0 + (size_t)arow * FD + (l >> 4) * 8);
    #pragma unroll
    for (int kf = 0; kf < 4; ++kf) {
      float4 f0 = ap[kf * 8];
      float4 f1 = ap[kf * 8 + 1];
      uint4 pk;
      pk.x = pack_bf2(f0.x, f0.y); pk.y = pack_bf2(f0.z, f0.w);
      pk.z = pack_bf2(f1.x, f1.y); pk.w = pack_bf2(f1.z, f1.w);
      a[kf] = *(bf16x8*)&pk;
    }
  } else {
    #pragma unroll
    for (int kf = 0; kf < 4; ++kf) a[kf] = (bf16x8)(short)0;
  }

  __syncthreads();

  f32x4 acc[8];
  #pragma unroll
  for (int nf = 0; nf < 8; ++nf) acc[nf] = (f32x4)(0.0f);
  #pragma unroll
  for (int nf = 0; nf < 8; ++nf)
    #pragma unroll
    for (int kf = 0; kf < 4; ++kf) {
      uint4 braw = bsh[(nf * 4 + kf) * 64 + l];
      acc[nf] = __builtin_amdgcn_mfma_f32_16x16x32_bf16(a[kf], *(bf16x8*)&braw, acc[nf], 0, 0, 0);
    }

  __syncthreads();   // all waves done reading W0

  #pragma unroll
  for (int it = 0; it < 8; ++it) {
    int s = it * 256 + tid;
    int nf = s >> 8, kf = (s >> 6) & 3, sl = s & 63;
    int col = nf * 16 + (sl & 15);
    bsh[s] = *(const uint4*)(Pt + col * FD + kf * 32 + (sl >> 4) * 8);
  }
  #pragma unroll
  for (int nf = 0; nf < 8; ++nf) {
    int col = nf * 16 + (l & 15);
    #pragma unroll
    for (int i = 0; i < 4; ++i) {
      int r = row0 + (l >> 4) * 4 + i;
      if (r < n) hw0[(size_t)r * FD + col] = f2bf(acc[nf][i]);
    }
  }

  __syncthreads();

  #pragma unroll
  for (int nf = 0; nf < 8; ++nf) acc[nf] = (f32x4)(0.0f);
  #pragma unroll
  for (int nf = 0; nf < 8; ++nf)
    #pragma unroll
    for (int kf = 0; kf < 4; ++kf) {
      uint4 braw = bsh[(nf * 4 + kf) * 64 + l];
      acc[nf] = __builtin_amdgcn_mfma_f32_16x16x32_bf16(a[kf], *(bf16x8*)&braw, acc[nf], 0, 0, 0);
    }
  #pragma unroll
  for (int nf = 0; nf < 8; ++nf) {
    int col = nf * 16 + (l & 15);
    #pragma unroll
    for (int i = 0; i < 4; ++i) {
      int r = row0 + (l >> 4) * 4 + i;
      if (r < n) xp[(size_t)r * FD + col] = f2bf(acc[nf][i]);
    }
  }
}

// ---------------- MFMA GEMM with fused GraphNorm-finalize + apply in A-loader ----------------
template<int EPI>
__global__ __launch_bounds__(256) void mfma_gemm(const unsigned short* __restrict__ Ab,
    const unsigned short* __restrict__ Wtb, void* __restrict__ Cout, int n,
    const float* __restrict__ bias, const float* __restrict__ hw, const float* __restrict__ hb,
    const float* __restrict__ colsum, const float* __restrict__ colsum2,
    const float* __restrict__ gnw, const float* __restrict__ gnb, const float* __restrict__ gnms,
    float inv_n, const unsigned short* __restrict__ residA, unsigned short* __restrict__ xout)
{
  __shared__ uint4 bsh[2048];
  __shared__ __align__(16) float svs[128];
  __shared__ __align__(16) float tvs[128];
  const int tid = threadIdx.x;
  const int l = tid & 63;
  const int w = tid >> 6;
  const int row0 = blockIdx.x * 64 + w * 16;

  #pragma unroll
  for (int it = 0; it < 8; ++it) {
    int s = it * 256 + tid;
    int nf = s >> 8, kf = (s >> 6) & 3, sl = s & 63;
    int col = nf * 16 + (sl & 15);
    bsh[s] = *(const uint4*)(Wtb + col * FD + kf * 32 + (sl >> 4) * 8);
  }
  if (tid < 128) {
    float mean = colsum[tid] * inv_n;
    float m2 = colsum2[tid] * inv_n;
    float m = gnms[tid];
    float var = m2 - 2.f * m * mean * mean + m * m * mean * mean;
    float sc = gnw[tid] * rsqrtf(var + 1e-5f);
    svs[tid] = sc;
    tvs[tid] = gnb[tid] - m * mean * sc;
  }
  __syncthreads();

  const int arow = row0 + (l & 15);
  bf16x8 a[4];
  if (arow < n) {
    const uint4* agp = (const uint4*)(Ab + (size_t)arow * FD + (l >> 4) * 8);
    const uint4* rsp = (const uint4*)(residA + (size_t)arow * FD + (l >> 4) * 8);
    uint4* xop = xout ? (uint4*)(xout + (size_t)arow * FD + (l >> 4) * 8) : nullptr;
    #pragma unroll
    for (int kf = 0; kf < 4; ++kf) {
      uint4 ag = agp[kf * 4];
      uint4 rs = rsp[kf * 4];
      int cb4 = kf * 8 + (l >> 4) * 2;
      float4 s0 = ((const float4*)svs)[cb4];
      float4 s1 = ((const float4*)svs)[cb4 + 1];
      float4 t0 = ((const float4*)tvs)[cb4];
      float4 t1 = ((const float4*)tvs)[cb4 + 1];
      uint4 pk;
      pk.x = pack_bf2(fmaxf(fmaf(bf_lo(ag.x), s0.x, t0.x), 0.f) + bf_lo(rs.x),
                      fmaxf(fmaf(bf_hi(ag.x), s0.y, t0.y), 0.f) + bf_hi(rs.x));
      pk.y = pack_bf2(fmaxf(fmaf(bf_lo(ag.y), s0.z, t0.z), 0.f) + bf_lo(rs.y),
                      fmaxf(fmaf(bf_hi(ag.y), s0.w, t0.w), 0.f) + bf_hi(rs.y));
      pk.z = pack_bf2(fmaxf(fmaf(bf_lo(ag.z), s1.x, t1.x), 0.f) + bf_lo(rs.z),
                      fmaxf(fmaf(bf_hi(ag.z), s1.y, t1.y), 0.f) + bf_hi(rs.z));
      pk.w = pack_bf2(fmaxf(fmaf(bf_lo(ag.w), s1.z, t1.z), 0.f) + bf_lo(rs.w),
                      fmaxf(fmaf(bf_hi(ag.w), s1.w, t1.w), 0.f) + bf_hi(rs.w));
      a[kf] = *(bf16x8*)&pk;
      if (xop) xop[kf * 4] = pk;
    }
  } else {
    #pragma unroll
    for (int kf = 0; kf < 4; ++kf) a[kf] = (bf16x8)(short)0;
  }

  __syncthreads();

  f32x4 acc[8];
  #pragma unroll
  for (int nf = 0; nf < 8; ++nf) acc[nf] = (f32x4)(0.0f);
  #pragma unroll
  for (int nf = 0; nf < 8; ++nf)
    #pragma unroll
    for (int kf = 0; kf < 4; ++kf) {
      uint4 braw = bsh[(nf * 4 + kf) * 64 + l];
      acc[nf] = __builtin_amdgcn_mfma_f32_16x16x32_bf16(a[kf], *(bf16x8*)&braw, acc[nf], 0, 0, 0);
    }

  if (EPI == 2) {
    float hsum[4] = {0.f, 0.f, 0.f, 0.f};
    #pragma unroll
    for (int nf = 0; nf < 8; ++nf) {
      int col = nf * 16 + (l & 15);
      float bm = bias[col];
      float hwc = hw[col];
      #pragma unroll
      for (int i = 0; i < 4; ++i)
        hsum[i] += fmaxf(acc[nf][i] + bm, 0.f) * hwc;
    }
    #pragma unroll
    for (int i = 0; i < 4; ++i) {
      #pragma unroll
      for (int off = 1; off < 16; off <<= 1) hsum[i] += __shfl_xor(hsum[i], off);
    }
    if ((l & 15) == 0) {
      float hb0 = hb[0];
      #pragma unroll
      for (int i = 0; i < 4; ++i) {
        int r = row0 + (l >> 4) * 4 + i;
        if (r < n) ((float*)Cout)[r] = hsum[i] + hb0;
      }
    }
  } else {
    unsigned short* outp = (unsigned short*)Cout;
    #pragma unroll
    for (int nf = 0; nf < 8; ++nf) {
      int col = nf * 16 + (l & 15);
      #pragma unroll
      for (int i = 0; i < 4; ++i) {
        int r = row0 + (l >> 4) * 4 + i;
        if (r < n) outp[(size_t)r * FD + col] = f2bf(acc[nf][i]);
      }
    }
  }
}

// ---------------- aggregation (bf16 rows) + fused GraphNorm stats ----------------
// Grid-stride, 4 streams/wave (16 lanes x uint4 = full 256B row), edge loop unrolled x4,
// row header pipelined. Wave's 4 streams process 4 CONSECUTIVE rows -> coalesced
// self-row loads and agg stores. agg stores are non-temporal: keep L2 for the gather table.
__device__ __forceinline__ void acc8(float* a, uint4 u, float wn) {
  a[0] = fmaf(wn, bf_lo(u.x), a[0]); a[1] = fmaf(wn, bf_hi(u.x), a[1]);
  a[2] = fmaf(wn, bf_lo(u.y), a[2]); a[3] = fmaf(wn, bf_hi(u.y), a[3]);
  a[4] = fmaf(wn, bf_lo(u.z), a[4]); a[5] = fmaf(wn, bf_hi(u.z), a[5]);
  a[6] = fmaf(wn, bf_lo(u.w), a[6]); a[7] = fmaf(wn, bf_hi(u.w), a[7]);
}

__global__ __launch_bounds__(256) void agg_bf16(const uint4* __restrict__ hw4, uint4* __restrict__ agg4,
    const int* __restrict__ indptr, const int* __restrict__ csr_src, const float* __restrict__ csr_norm,
    const float* __restrict__ dinv, const float* __restrict__ bias,
    float* __restrict__ colsum, float* __restrict__ colsum2, int n)
{
  __shared__ float sredS[4][16][9];
  __shared__ float sredQ[4][16][9];
  const int wv = threadIdx.x >> 6;
  const int lane = threadIdx.x & 63;
  const int q = lane >> 4;
  const int l16 = lane & 15;
  const int gs = blockIdx.x * 16 + wv * 4 + q;
  const int ns = gridDim.x * 16;
  const float4 b0 = ((const float4*)bias)[l16 * 2];
  const float4 b1 = ((const float4*)bias)[l16 * 2 + 1];
  float st[8], sq[8];
  #pragma unroll
  for (int j = 0; j < 8; ++j) { st[j] = 0.f; sq[j] = 0.f; }

  int c = gs;
  float di = 0.f; int e0 = 0, e1 = 0;
  uint4 su = make_uint4(0, 0, 0, 0);
  if (c < n) {
    di = dinv[c];
    e0 = indptr[c]; e1 = indptr[c + 1];
    su = hw4[(size_t)c * 16 + l16];
  }
  while (c < n) {
    const int cn = c + ns;
    float di_n = 0.f; int e0_n = 0, e1_n = 0;
    uint4 su_n = make_uint4(0, 0, 0, 0);
    if (cn < n) {
      di_n = dinv[cn];
      e0_n = indptr[cn]; e1_n = indptr[cn + 1];
      su_n = hw4[(size_t)cn * 16 + l16];
    }

    float self = di * di;
    float a[8];
    a[0] = fmaf(self, bf_lo(su.x), b0.x); a[1] = fmaf(self, bf_hi(su.x), b0.y);
    a[2] = fmaf(self, bf_lo(su.y), b0.z); a[3] = fmaf(self, bf_hi(su.y), b0.w);
    a[4] = fmaf(self, bf_lo(su.z), b1.x); a[5] = fmaf(self, bf_hi(su.z), b1.y);
    a[6] = fmaf(self, bf_lo(su.w), b1.z); a[7] = fmaf(self, bf_hi(su.w), b1.w);
    int e = e0;
    for (; e + 4 <= e1; e += 4) {
      int s0 = csr_src[e], s1 = csr_src[e + 1], s2 = csr_src[e + 2], s3 = csr_src[e + 3];
      float w0 = csr_norm[e], w1 = csr_norm[e + 1], w2 = csr_norm[e + 2], w3 = csr_norm[e + 3];
      uint4 u0 = hw4[(size_t)s0 * 16 + l16];
      uint4 u1 = hw4[(size_t)s1 * 16 + l16];
      uint4 u2 = hw4[(size_t)s2 * 16 + l16];
      uint4 u3 = hw4[(size_t)s3 * 16 + l16];
      acc8(a, u0, w0); acc8(a, u1, w1); acc8(a, u2, w2); acc8(a, u3, w3);
    }
    if (e + 2 <= e1) {
      int s0 = csr_src[e], s1 = csr_src[e + 1];
      float w0 = csr_norm[e], w1 = csr_norm[e + 1];
      uint4 u0 = hw4[(size_t)s0 * 16 + l16];
      uint4 u1 = hw4[(size_t)s1 * 16 + l16];
      acc8(a, u0, w0); acc8(a, u1, w1);
      e += 2;
    }
    if (e < e1) {
      int s0 = csr_src[e];
      float w0 = csr_norm[e];
      uint4 u0 = hw4[(size_t)s0 * 16 + l16];
      acc8(a, u0, w0);
    }
    uint4v o;
    o.x = pack_bf2(a[0], a[1]); o.y = pack_bf2(a[2], a[3]);
    o.z = pack_bf2(a[4], a[5]); o.w = pack_bf2(a[6], a[7]);
    __builtin_nontemporal_store(o, (uint4v*)&agg4[(size_t)c * 16 + l16]);
    #pragma unroll
    for (int j = 0; j < 8; ++j) { st[j] += a[j]; sq[j] += a[j] * a[j]; }

    c = cn; di = di_n; e0 = e0_n; e1 = e1_n; su = su_n;
  }

  #pragma unroll
  for (int j = 0; j < 8; ++j) {
    st[j] += __shfl_xor(st[j], 16); st[j] += __shfl_xor(st[j], 32);
    sq[j] += __shfl_xor(sq[j], 16); sq[j] += __shfl_xor(sq[j], 32);
  }
  if (q == 0) {
    #pragma unroll
    for (int j = 0; j < 8; ++j) { sredS[wv][l16][j] = st[j]; sredQ[wv][l16][j] = sq[j]; }
  }
  __syncthreads();
  int t = threadIdx.x;
  int which = t >> 7, cc = t & 127;
  int rl = cc >> 3, rk = cc & 7;
  float v = 0.f;
  #pragma unroll
  for (int w2 = 0; w2 < 4; ++w2)
    v += which ? sredQ[w2][rl][rk] : sredS[w2][rl][rk];
  atomicAdd(which ? &colsum2[cc] : &colsum[cc], v);
}

// ---------------- launcher ----------------
extern "C" void kernel_launch(void* const* d_in, const int* in_sizes, int n_in,
                              void* d_out, int out_size, void* d_ws, size_t ws_size,
                              hipStream_t stream) {
  const float* x0      = (const float*)d_in[0];
  const int* ei        = (const int*)d_in[1];   // int32 per harness conversion
  const float* conv_w  = (const float*)d_in[2];
  const float* conv_b  = (const float*)d_in[3];
  const float* gn_w    = (const float*)d_in[4];
  const float* gn_b    = (const float*)d_in[5];
  const float* gn_ms   = (const float*)d_in[6];
  const float* proj_w  = (const float*)d_in[7];
  const float* mlp_w   = (const float*)d_in[8];
  const float* mlp_b   = (const float*)d_in[9];
  const float* head_w  = (const float*)d_in[10];
  const float* head_b  = (const float*)d_in[11];
  float* out = (float*)d_out;

  const int n = in_sizes[0] / FD;
  const int e = in_sizes[1] / 2;
  const size_t ND = (size_t)n * FD;

  unsigned short* hwb  = (unsigned short*)d_ws;  // hw per layer
  unsigned short* aggb = hwb + ND;               // agg per layer
  unsigned short* xpb  = aggb + ND;              // xp (x0@proj), later x2
  unsigned short* xrb  = xpb + ND;               // x1
  unsigned short* Wtb  = xrb + ND;               // 5 * 16384 bf16
  float* csr_norm = (float*)(Wtb + 5 * 16384);
  float* dinv     = csr_norm + e;
  float* stats    = dinv + n;                    // colsum[3][128] then colsum2[3][128]
  int* deg      = (int*)(stats + 768);
  int* fill     = deg + n;
  int* indptr   = fill + n;
  int* tmp      = indptr + (n + 1);
  int* partials = tmp + n;
  int* csr_src  = partials + 1024;

  const int nb256_n = (n + 255) / 256;
  const int nb256_e = (e + 255) / 256;
  const int nb128_n = (n + 127) / 128;

  // ---- graph preprocessing ----
  init_kernel<<<nb256_n, 256, 0, stream>>>(deg, fill, stats, n);
  edge_count_kernel<<<nb256_e, 256, 0, stream>>>(ei, e, deg);
  scan1_kernel<<<nb128_n, 128, 0, stream>>>(deg, n, tmp, partials, dinv);
  scan2_kernel<<<1, 1024, 0, stream>>>(partials, nb128_n);
  scan3_kernel<<<nb128_n, 128, 0, stream>>>(tmp, partials, indptr, n);
  fill_kernel<<<nb256_e, 256, 0, stream>>>(ei, e, indptr, fill, dinv, csr_src, csr_norm);

  // ---- bf16 weight prep ----
  prep_w<<<320, 256, 0, stream>>>(conv_w, proj_w, mlp_w, Wtb);

  const int gemm_grid = (n + 63) / 64;
  const float inv_n = 1.f / (float)n;
  const unsigned short* Wt_conv0 = Wtb;
  const unsigned short* Wt_conv1 = Wtb + 16384;
  const unsigned short* Wt_conv2 = Wtb + 2 * 16384;
  const unsigned short* Wt_proj  = Wtb + 3 * 16384;
  const unsigned short* Wt_mlp   = Wtb + 4 * 16384;

  // ---- layer 0: hw0 = x0@W0 and xp = x0@proj in one kernel ----
  gemm_dual<<<gemm_grid, 256, 0, stream>>>(x0, Wt_conv0, Wt_proj, hwb, xpb, n);
  agg_bf16<<<2048, 256, 0, stream>>>((const uint4*)hwb, (uint4*)aggb, indptr, csr_src, csr_norm, dinv,
      conv_b + 0 * FD, stats + 0 * FD, stats + 384 + 0 * FD, n);

  // ---- layer 1: A = x1 = relu(agg0*s0+t0)+xp (finalize fused), writes x1 -> xrb, C = hw1 ----
  mfma_gemm<0><<<gemm_grid, 256, 0, stream>>>(aggb, Wt_conv1, hwb, n,
      nullptr, nullptr, nullptr, stats + 0 * FD, stats + 384 + 0 * FD,
      gn_w + 0 * FD, gn_b + 0 * FD, gn_ms + 0 * FD, inv_n, xpb, xrb);
  agg_bf16<<<2048, 256, 0, stream>>>((const uint4*)hwb, (uint4*)aggb, indptr, csr_src, csr_norm, dinv,
      conv_b + 1 * FD, stats + 1 * FD, stats + 384 + 1 * FD, n);

  // ---- layer 2: A = x2 = relu(agg1*s1+t1)+x1, writes x2 -> xpb, C = hw2 ----
  mfma_gemm<0><<<gemm_grid, 256, 0, stream>>>(aggb, Wt_conv2, hwb, n,
      nullptr, nullptr, nullptr, stats + 1 * FD, stats + 384 + 1 * FD,
      gn_w + 1 * FD, gn_b + 1 * FD, gn_ms + 1 * FD, inv_n, xrb, xpb);
  agg_bf16<<<2048, 256, 0, stream>>>((const uint4*)hwb, (uint4*)aggb, indptr, csr_src, csr_norm, dinv,
      conv_b + 2 * FD, stats + 2 * FD, stats + 384 + 2 * FD, n);

  // ---- MLP + head: A = x3 = relu(agg2*s2+t2)+x2 inline, f32 out ----
  mfma_gemm<2><<<gemm_grid, 256, 0, stream>>>(aggb, Wt_mlp, out, n,
      mlp_b, head_w, head_b, stats + 2 * FD, stats + 384 + 2 * FD,
      gn_w + 2 * FD, gn_b + 2 * FD, gn_ms + 2 * FD, inv_n, xpb, nullptr);
}